// Round 7
// baseline (86.864 us; speedup 1.0000x reference)
//
#include <hip/hip_runtime.h>
#include <cstdint>
#include <cmath>

// ---------------------------------------------------------------------------
// KDNet: 11x fused { pointwise conv + ReLU + kd-gather + pair-maxpool }, then
// FC(1024->16) + log_softmax.  Multi-launch structure (cooperative grid.sync
// measured ~100us/sync on 8 XCDs — 6x worse; do not revisit).
//
//   e = 3d + sel[d]; q = e/dim; p = e%dim   (batch-uniform per position d)
//   pre[b,f,d] = dot(W[3f+q,:], x[b,:,p]) + bias[3f+q]
//   out[b,f,j] = relu(max(pre[.,.,2j], pre[.,.,2j+1]))
//
// chain history: r1 46us (per-block W f2bf); r2 40us (LDS W, exposed
// staging); r3 50us REGRESSED (direct-global frags); r4 ~25us WIN (T14
// bhalf8 reg-prefetch); r5 82.3 total (l01 fused in); r6 86.7 REGRESSED —
// fp32 W prefetch doubled prefetch VGPRs (w5r 48 regs live across kdlayer)
// -> spills at VGPR=64 (VALUBusy 28->40%, FETCH +6MB).  r7: revert W to
// pre-converted bf16 (wprep25 kernel) + bhalf8 prefetch; KEEP r6's x-LDS
// staging + qp0 table and the kdmfma2 tail (barrier-skip, BT=16 L9/L10).
//
// chain LDS pool 79872B (2 blk/CU):
//   qp tables @0..2048 persistent (qp2,qp3,qp4,qp5)
//   IN @2048 (32K, dies after L2 A-loads)     W2 @34816 (12K, dies after L2)
//   W0s/b0s/W1s/b1s @47104 (3.8K, dies at B1) xs @51200 (24K f32, dies at B1)
//   qp0 @75776 (4K, dies at B1)
//   O2 @47104 (32K, L2->L3)                   W3 @2048  (24K, over dead IN)
//   O3 @26624 (16K, L3->L4)                   W4 @47104 (24K, over dead O2)
//   O4 @71680 (8K, L4->L5)                    W5 @2048  (48K, over dead W3/O3)
//   O5 @51200 (8K, over dead W4/xs)
// All W/O tiles XOR-slot-swizzled: byte ^= (row&SM)<<4.
// ---------------------------------------------------------------------------

typedef __attribute__((ext_vector_type(8))) short bhalf8;
typedef __attribute__((ext_vector_type(4))) float floatx4;

__device__ __forceinline__ unsigned short f2bf(float f) {
    uint32_t u = __float_as_uint(f);
    u += 0x7FFFu + ((u >> 16) & 1u);          // round-to-nearest-even
    return (unsigned short)(u >> 16);
}
__device__ __forceinline__ float bf2f(unsigned short u) {
    return __uint_as_float(((uint32_t)u) << 16);
}

struct WPrep {
    const float* src[5];
    unsigned short* dst[5];
    int n4[5];
};

// ---- W2..W5 fp32 -> bf16 linear (tiny; must precede chain) ----
__global__ __launch_bounds__(256)
void wprep25_kernel(WPrep wp) {
    const int stride = gridDim.x * 256;
    const int g0 = blockIdx.x * 256 + threadIdx.x;
    #pragma unroll
    for (int l = 0; l < 4; ++l) {
        const float4* s = reinterpret_cast<const float4*>(wp.src[l]);
        uint2* d = reinterpret_cast<uint2*>(wp.dst[l]);
        for (int i = g0; i < wp.n4[l]; i += stride) {
            const float4 v = s[i];
            uint2 o;
            o.x = (uint32_t)f2bf(v.x) | ((uint32_t)f2bf(v.y) << 16);
            o.y = (uint32_t)f2bf(v.z) | ((uint32_t)f2bf(v.w) << 16);
            d[i] = o;
        }
    }
}

template<int RB>
__device__ __forceinline__ int swaddr(int row, int colbyte) {
    constexpr int SM = (RB / 16 >= 8) ? 7 : (RB / 16 - 1);
    return row * RB + (colbyte ^ ((row & SM) << 4));
}

// 16B-granule index -> swizzled byte offset for a tile with CIN elems/row
template<int CIN>
__device__ __forceinline__ int wswz(int i) {
    constexpr int GPR = CIN / 8;          // granules per row
    constexpr int RB  = CIN * 2;
    const int row = i / GPR, c = i - row * GPR;
    return swaddr<RB>(row, c * 16);
}

template<int DIM, int CIN, int FEAT>
__device__ __forceinline__ void kdlayer(char* pool, int offIn, int offOut,
                                        int qpOff, int offW,
                                        const float* __restrict__ bg, int tid) {
    constexpr int NH  = CIN / 32;      // mfma k-slices
    constexpr int MT  = DIM / 16;      // M tiles (gathered rows)
    constexpr int NT  = FEAT / 16;     // N tiles
    constexpr int RBW = CIN * 2;       // row bytes, input + weight tiles
    constexpr int RBO = FEAT * 2;      // row bytes, output tile
    constexpr int WM  = (MT < 8) ? MT : 8;   // waves over M
    constexpr int WN  = 8 / WM;              // waves over N
    constexpr int MPW = MT / WM;             // M tiles per wave
    constexpr int NPW = NT / WN;             // N tiles per wave

    const unsigned short* qp = (const unsigned short*)(pool + qpOff);
    const int wv = tid >> 6, ln = tid & 63;
    const int g = ln >> 4, l15 = ln & 15;
    const int wm = wv % WM, wn = wv / WM;

    // A-frags + q-codes for this wave's M tiles
    bhalf8 aC[MPW][NH];
    uint32_t qpk[MPW];                 // 4x4-bit q per acc row
    #pragma unroll
    for (int i = 0; i < MPW; ++i) {
        const int mt = wm + i * WM;
        const int pa = qp[mt * 16 + l15] & 0xFFF;
        #pragma unroll
        for (int ks = 0; ks < NH; ++ks)
            aC[i][ks] = *(const bhalf8*)(pool + offIn +
                          swaddr<RBW>(pa, (ks * 32 + g * 8) * 2));
        const ushort4 qq = *(const ushort4*)(qp + mt * 16 + g * 4);
        qpk[i] = (uint32_t)(qq.x >> 12) | ((uint32_t)(qq.y >> 12) << 4)
               | ((uint32_t)(qq.z >> 12) << 8) | ((uint32_t)(qq.w >> 12) << 12);
    }

    #pragma unroll
    for (int ntj = 0; ntj < NPW; ++ntj) {
        const int nt = wn * NPW + ntj;
        const int f = nt * 16 + l15;
        bhalf8 bF[3][NH];              // B frags from LDS, once per nt
        #pragma unroll
        for (int q = 0; q < 3; ++q)
            #pragma unroll
            for (int ks = 0; ks < NH; ++ks)
                bF[q][ks] = *(const bhalf8*)(pool + offW +
                              swaddr<RBW>(3 * f + q, (ks * 32 + g * 8) * 2));
        const float bv0 = bg[3 * f + 0];
        const float bv1 = bg[3 * f + 1];
        const float bv2 = bg[3 * f + 2];
        #pragma unroll
        for (int i = 0; i < MPW; ++i) {
            floatx4 a0 = (floatx4){0.f,0.f,0.f,0.f};
            floatx4 a1 = (floatx4){0.f,0.f,0.f,0.f};
            floatx4 a2 = (floatx4){0.f,0.f,0.f,0.f};
            #pragma unroll
            for (int ks = 0; ks < NH; ++ks) {
                a0 = __builtin_amdgcn_mfma_f32_16x16x32_bf16(aC[i][ks], bF[0][ks], a0, 0, 0, 0);
                a1 = __builtin_amdgcn_mfma_f32_16x16x32_bf16(aC[i][ks], bF[1][ks], a1, 0, 0, 0);
                a2 = __builtin_amdgcn_mfma_f32_16x16x32_bf16(aC[i][ks], bF[2][ks], a2, 0, 0, 0);
            }
            const int mt = wm + i * WM;
            const int j0 = mt * 8 + g * 2;     // output row pair base
            float v[4];
            #pragma unroll
            for (int r = 0; r < 4; ++r) {
                const int qi = (qpk[i] >> (4 * r)) & 0xF;
                const float pre = (qi == 0) ? a0[r] : (qi == 1 ? a1[r] : a2[r]);
                const float bq  = (qi == 0) ? bv0  : (qi == 1 ? bv1  : bv2);
                v[r] = pre + bq;
            }
            *(unsigned short*)(pool + offOut + swaddr<RBO>(j0,     f * 2)) =
                f2bf(fmaxf(fmaxf(v[0], v[1]), 0.f));
            *(unsigned short*)(pool + offOut + swaddr<RBO>(j0 + 1, f * 2)) =
                f2bf(fmaxf(fmaxf(v[2], v[3]), 0.f));
        }
    }
}

__global__ __launch_bounds__(512, 4)
void chain_kernel(const float* __restrict__ x,                 // [B,3,2048]
                  const float* __restrict__ W0, const float* __restrict__ b0f,
                  const int* __restrict__ sel0,
                  const float* __restrict__ W1, const float* __restrict__ b1f,
                  const int* __restrict__ sel1,
                  unsigned short* __restrict__ outp,           // [B,32,128]
                  const unsigned short* __restrict__ w2, const float* __restrict__ b2, const int* __restrict__ s2,
                  const unsigned short* __restrict__ w3, const float* __restrict__ b3, const int* __restrict__ s3,
                  const unsigned short* __restrict__ w4, const float* __restrict__ b4, const int* __restrict__ s4,
                  const unsigned short* __restrict__ w5, const float* __restrict__ b5, const int* __restrict__ s5,
                  WPrep wp, int nrows) {
    const int tid = threadIdx.x;

    if ((int)blockIdx.x >= nrows) {            // ---- W6..W10 prep blocks ----
        const int stride = (gridDim.x - nrows) * 512;
        const int g0 = (blockIdx.x - nrows) * 512 + tid;
        #pragma unroll
        for (int l = 0; l < 5; ++l) {
            const float4* s = reinterpret_cast<const float4*>(wp.src[l]);
            uint2* d = reinterpret_cast<uint2*>(wp.dst[l]);
            for (int i = g0; i < wp.n4[l]; i += stride) {
                const float4 v = s[i];
                uint2 o;
                o.x = (uint32_t)f2bf(v.x) | ((uint32_t)f2bf(v.y) << 16);
                o.y = (uint32_t)f2bf(v.z) | ((uint32_t)f2bf(v.w) << 16);
                d[i] = o;
            }
        }
        return;
    }

    __shared__ __align__(16) char pool[79872];
    const int b = blockIdx.x;

    // ---- issue earliest loads: x row (coalesced), W2 + W3 bf16 ----
    const float4* xg = (const float4*)(x + (size_t)b * 6144);
    const float4 xr0 = xg[tid], xr1 = xg[512 + tid], xr2 = xg[1024 + tid];

    bhalf8 w2r[2];
    w2r[0] = ((const bhalf8*)w2)[tid];
    if (tid < 256) w2r[1] = ((const bhalf8*)w2)[512 + tid];

    bhalf8 w3r[3];
    #pragma unroll
    for (int u = 0; u < 3; ++u)
        w3r[u] = ((const bhalf8*)w3)[u * 512 + tid];

    // ---- stage L0/L1 weights (temp @47104) + qp tables + qp0 table ----
    float* W0s = (float*)(pool + 47104);       // [24][3]
    float* b0s = W0s + 72;                     // [24]
    float* W1s = b0s + 24;                     // [96][8]
    float* b1s = W1s + 768;                    // [96]
    if (tid < 24) {
        W0s[tid * 3 + 0] = W0[tid * 3 + 0];
        W0s[tid * 3 + 1] = W0[tid * 3 + 1];
        W0s[tid * 3 + 2] = W0[tid * 3 + 2];
        b0s[tid] = b0f[tid];
    }
    if (tid < 96) {
        #pragma unroll
        for (int k = 0; k < 8; ++k) W1s[tid * 8 + k] = W1[tid * 8 + k];
        b1s[tid] = b1f[tid];
    }
    {
        unsigned short* qp2 = (unsigned short*)(pool + 0);
        unsigned short* qp3 = (unsigned short*)(pool + 1024);
        unsigned short* qp4 = (unsigned short*)(pool + 1536);
        unsigned short* qp5 = (unsigned short*)(pool + 1792);
        { const int d = tid;
          const int e = 3 * d + s2[d];
          const int q = (e >= 512) + (e >= 1024);
          qp2[d] = (unsigned short)((q << 12) | (e - q * 512)); }
        if (tid < 256) { const int d = tid;
          const int e = 3 * d + s3[d];
          const int q = (e >= 256) + (e >= 512);
          qp3[d] = (unsigned short)((q << 12) | (e - q * 256)); }
        if (tid < 128) { const int d = tid;
          const int e = 3 * d + s4[d];
          const int q = (e >= 128) + (e >= 256);
          qp4[d] = (unsigned short)((q << 12) | (e - q * 128)); }
        if (tid < 64)  { const int d = tid;
          const int e = 3 * d + s5[d];
          const int q = (e >= 64) + (e >= 128);
          qp5[d] = (unsigned short)((q << 12) | (e - q * 64)); }
        // qp0: sel0 -> (q<<12 | p), 2048 entries @75776 (dies at B1)
        unsigned short* qp0 = (unsigned short*)(pool + 75776);
        #pragma unroll
        for (int it = 0; it < 4; ++it) {
            const int d = it * 512 + tid;
            const int e = 3 * d + sel0[d];
            const int q = (e >= 2048) + (e >= 4096);
            qp0[d] = (unsigned short)((q << 12) | (e - q * 2048));
        }
    }
    // ---- x -> LDS (linear f32 @51200, dies at B1) ----
    {
        float4* xs4 = (float4*)(pool + 51200);
        xs4[tid] = xr0; xs4[512 + tid] = xr1; xs4[1024 + tid] = xr2;
    }
    __syncthreads();                                   // B0

    // ---- fused L0+L1 for row b, position j1 = tid -> IN tile @2048 ----
    {
        const int j1 = tid;
        const float* xs = (const float*)(pool + 51200);
        const unsigned short* qp0 = (const unsigned short*)(pool + 75776);

        float cols[2][8];
        int q1v[2];
        #pragma unroll
        for (int pos1 = 0; pos1 < 2; ++pos1) {
            const int d1 = 2 * j1 + pos1;
            const int e1 = 3 * d1 + sel1[d1];
            const int q1 = (e1 >= 1024) + (e1 >= 2048);
            const int p1 = e1 - q1 * 1024;
            q1v[pos1] = q1;

            float xv[2][3]; int qq0[2];
            #pragma unroll
            for (int pos0 = 0; pos0 < 2; ++pos0) {
                const int c0 = qp0[2 * p1 + pos0];
                const int q0 = c0 >> 12;
                const int p0 = c0 & 0xFFF;
                qq0[pos0] = q0;
                xv[pos0][0] = xs[p0];
                xv[pos0][1] = xs[2048 + p0];
                xv[pos0][2] = xs[4096 + p0];
            }
            #pragma unroll
            for (int f = 0; f < 8; ++f) {
                const int r0 = 3 * f + qq0[0], r1 = 3 * f + qq0[1];
                const float v0 = b0s[r0] + W0s[r0*3+0]*xv[0][0] + W0s[r0*3+1]*xv[0][1] + W0s[r0*3+2]*xv[0][2];
                const float v1 = b0s[r1] + W0s[r1*3+0]*xv[1][0] + W0s[r1*3+1]*xv[1][1] + W0s[r1*3+2]*xv[1][2];
                cols[pos1][f] = fmaxf(fmaxf(v0, v1), 0.f);
            }
        }
        #pragma unroll
        for (int gi = 0; gi < 4; ++gi) {
            bhalf8 og;
            #pragma unroll
            for (int fk = 0; fk < 8; ++fk) {
                const int f = gi * 8 + fk;
                const int r0 = 3 * f + q1v[0], r1 = 3 * f + q1v[1];
                float v0 = b1s[r0], v1 = b1s[r1];
                #pragma unroll
                for (int k = 0; k < 8; ++k) {
                    v0 = fmaf(cols[0][k], W1s[r0*8+k], v0);
                    v1 = fmaf(cols[1][k], W1s[r1*8+k], v1);
                }
                og[fk] = (short)f2bf(fmaxf(fmaxf(v0, v1), 0.f));
            }
            *(bhalf8*)(pool + 2048 + swaddr<64>(j1, gi * 16)) = og;
        }
    }
    // W2 -> LDS (swizzled)
    *(bhalf8*)(pool + 34816 + wswz<32>(tid)) = w2r[0];
    if (tid < 256)
        *(bhalf8*)(pool + 34816 + wswz<32>(512 + tid)) = w2r[1];
    __syncthreads();                                   // B1: IN + W2 ready

    kdlayer<512, 32, 64>(pool, 2048, 47104, 0, 34816, b2, tid);
    __syncthreads();                                   // B2: O2 ready, IN dead

    // W3 -> LDS (over dead IN); prefetch W4
    bhalf8 w4r[3];
    #pragma unroll
    for (int u = 0; u < 3; ++u)
        w4r[u] = ((const bhalf8*)w4)[u * 512 + tid];
    #pragma unroll
    for (int u = 0; u < 3; ++u)
        *(bhalf8*)(pool + 2048 + wswz<64>(u * 512 + tid)) = w3r[u];
    __syncthreads();                                   // B3: W3 visible

    kdlayer<256, 64, 64>(pool, 47104, 26624, 1024, 2048, b3, tid);
    __syncthreads();                                   // B4: O3 ready, O2/W3 dead

    // W4 -> LDS (over dead O2); prefetch W5
    bhalf8 w5r[6];
    #pragma unroll
    for (int u = 0; u < 6; ++u)
        w5r[u] = ((const bhalf8*)w5)[u * 512 + tid];
    #pragma unroll
    for (int u = 0; u < 3; ++u)
        *(bhalf8*)(pool + 47104 + wswz<64>(u * 512 + tid)) = w4r[u];
    __syncthreads();                                   // B5: W4 visible

    kdlayer<128, 64, 64>(pool, 26624, 71680, 1536, 47104, b4, tid);
    __syncthreads();                                   // B6: O4 ready, O3/W4 dead

    // W5 -> LDS (over dead W3/O3)
    #pragma unroll
    for (int u = 0; u < 6; ++u)
        *(bhalf8*)(pool + 2048 + wswz<64>(u * 512 + tid)) = w5r[u];
    __syncthreads();                                   // B7: W5 visible

    kdlayer<64, 64, 128>(pool, 71680, 51200, 1792, 2048, b5, tid);
    __syncthreads();                                   // B8: O5 ready

    // write out O5 [32][128] bf16: unswizzle on read, coalesced global store
    {
        char* dst = (char*)(outp + (size_t)b * 32 * 128);
        const int off = tid * 16;
        const bhalf8 v = *(const bhalf8*)(pool + 51200 +
                                          swaddr<256>(off >> 8, off & 255));
        *(bhalf8*)(dst + off) = v;
    }
}

// ---------------------------------------------------------------------------
// kdmfma2: tail GEMM layers (L6..L10).  Stages BOTH positions per k-stage
// (Ab[2]/Wb[2]); barrier pairs = CIN/128 (first pre-write barrier skipped).
// BT=32: MF=2 (L6..L8); BT=16: MF=1 (L9/L10 — doubles grid for overlap).
// Per-acc k-slice order identical to the original kdmfma (bitwise same).
// ---------------------------------------------------------------------------
template<int CIN, int BT>
__global__ __launch_bounds__(256)
void kdmfma2_kernel(const unsigned short* __restrict__ act,
                    const unsigned short* __restrict__ Wq,
                    const float* __restrict__ bias,
                    const int*   __restrict__ sel,
                    unsigned short* __restrict__ out,
                    int feat, int dim, int nbt) {
    constexpr int KS  = 128;
    constexpr int NH  = KS / 32;              // 4
    constexpr int LDK = KS + 8;
    constexpr int TPA = 256 / BT;
    constexpr int EA  = KS / TPA;
    constexpr int NSA = EA / 8;
    constexpr int NSW = KS / 32;              // 4
    constexpr int MF  = BT / 16;
    __shared__ __align__(16) unsigned short Ab[2][BT][LDK];
    __shared__ __align__(16) unsigned short Wb[2][64][LDK];

    const int dimh = dim >> 1;
    const int bt = blockIdx.x % nbt;
    const int j  = blockIdx.x / nbt;
    const int f0 = blockIdx.y * 64;
    const int b0 = bt * BT;

    const int tid  = threadIdx.x;
    const int lane = tid & 63;
    const int wave = tid >> 6;

    const int srowA = tid / TPA;
    const int kgA   = (tid % TPA) * EA;
    const int srowW = tid >> 2;
    const int kgW   = (tid & 3) * (KS / 4);
    const int colBase = wave * 16;

    int qv[2];
    const unsigned short* Ap[2];
    const unsigned short* Wp[2];
    #pragma unroll
    for (int pp = 0; pp < 2; ++pp) {
        const int d = 2 * j + pp;
        const int e = 3 * d + sel[d];
        const int q = (e >= dim) + (e >= 2 * dim);
        const int p = e - q * dim;
        qv[pp] = q;
        Ap[pp] = act + ((size_t)(b0 + srowA) * dim + p) * CIN + kgA;
        Wp[pp] = Wq + ((size_t)(3 * (f0 + srowW) + q)) * CIN + kgW;
    }

    floatx4 acc[2][MF];
    #pragma unroll
    for (int pp = 0; pp < 2; ++pp)
        #pragma unroll
        for (int mi = 0; mi < MF; ++mi)
            acc[pp][mi] = (floatx4){0.f, 0.f, 0.f, 0.f};

    bhalf8 pa[2][NSA], pw[2][NSW];
    #pragma unroll
    for (int pp = 0; pp < 2; ++pp) {
        #pragma unroll
        for (int u = 0; u < NSA; ++u)
            pa[pp][u] = *reinterpret_cast<const bhalf8*>(Ap[pp] + u * 8);
        #pragma unroll
        for (int u = 0; u < NSW; ++u)
            pw[pp][u] = *reinterpret_cast<const bhalf8*>(Wp[pp] + u * 8);
    }

    for (int k0 = 0; k0 < CIN; k0 += KS) {
        if (k0) __syncthreads();   // protect prior stage's fragment reads
        #pragma unroll
        for (int pp = 0; pp < 2; ++pp) {
            #pragma unroll
            for (int u = 0; u < NSA; ++u)
                *reinterpret_cast<bhalf8*>(&Ab[pp][srowA][kgA + u * 8]) = pa[pp][u];
            #pragma unroll
            for (int u = 0; u < NSW; ++u)
                *reinterpret_cast<bhalf8*>(&Wb[pp][srowW][kgW + u * 8]) = pw[pp][u];
        }
        if (k0 + KS < CIN) {
            #pragma unroll
            for (int pp = 0; pp < 2; ++pp) {
                #pragma unroll
                for (int u = 0; u < NSA; ++u)
                    pa[pp][u] = *reinterpret_cast<const bhalf8*>(Ap[pp] + k0 + KS + u * 8);
                #pragma unroll
                for (int u = 0; u < NSW; ++u)
                    pw[pp][u] = *reinterpret_cast<const bhalf8*>(Wp[pp] + k0 + KS + u * 8);
            }
        }
        __syncthreads();

        #pragma unroll
        for (int ks = 0; ks < NH; ++ks) {
            const int kk = ks * 32 + (lane >> 4) * 8;
            bhalf8 aF[2][MF], bF[2];
            #pragma unroll
            for (int pp = 0; pp < 2; ++pp) {
                #pragma unroll
                for (int mi = 0; mi < MF; ++mi)
                    aF[pp][mi] = *reinterpret_cast<const bhalf8*>(
                        &Ab[pp][mi * 16 + (lane & 15)][kk]);
                bF[pp] = *reinterpret_cast<const bhalf8*>(
                        &Wb[pp][colBase + (lane & 15)][kk]);
            }
            #pragma unroll
            for (int pp = 0; pp < 2; ++pp)
                #pragma unroll
                for (int mi = 0; mi < MF; ++mi)
                    acc[pp][mi] = __builtin_amdgcn_mfma_f32_16x16x32_bf16(
                        aF[pp][mi], bF[pp], acc[pp][mi], 0, 0, 0);
        }
    }

    const int orow = (lane >> 4) << 2;
    const int ocol = lane & 15;
    #pragma unroll
    for (int mi = 0; mi < MF; ++mi) {
        const int fc = f0 + colBase + ocol;
        const float bv0 = bias[3 * fc + qv[0]];
        const float bv1 = bias[3 * fc + qv[1]];
        #pragma unroll
        for (int i = 0; i < 4; ++i) {
            const int br = b0 + mi * 16 + orow + i;
            const float v = fmaxf(fmaxf(acc[0][mi][i] + bv0,
                                        acc[1][mi][i] + bv1), 0.f);
            out[((size_t)br * dimh + j) * feat + fc] = f2bf(v);
        }
    }
}

// FC (1024 -> 16) + log_softmax; input bf16 [B, 1024].
__global__ __launch_bounds__(256)
void fc_lsm_kernel(const unsigned short* __restrict__ y,
                   const float* __restrict__ Wfc,
                   const float* __restrict__ bfc,
                   float* __restrict__ out) {
    const int b   = blockIdx.x;
    const int tid = threadIdx.x;
    __shared__ __align__(16) float ys[1024];
    __shared__ float lg[16];

    {
        const ushort4 v = reinterpret_cast<const ushort4*>(y + (size_t)b * 1024)[tid];
        ys[tid * 4 + 0] = bf2f(v.x);
        ys[tid * 4 + 1] = bf2f(v.y);
        ys[tid * 4 + 2] = bf2f(v.z);
        ys[tid * 4 + 3] = bf2f(v.w);
    }
    __syncthreads();

    const int l = tid >> 4, lane = tid & 15;
    const float4* w4 = reinterpret_cast<const float4*>(Wfc + (size_t)l * 1024);
    const float4* y4 = reinterpret_cast<const float4*>(ys);
    float p = 0.f;
    #pragma unroll
    for (int i = 0; i < 16; ++i) {
        const float4 a = y4[lane + 16 * i];
        const float4 w = w4[lane + 16 * i];
        p += a.x * w.x + a.y * w.y + a.z * w.z + a.w * w.w;
    }
    #pragma unroll
    for (int off = 8; off > 0; off >>= 1) p += __shfl_down(p, off, 16);
    if (lane == 0) lg[l] = p + bfc[l];
    __syncthreads();

    if (tid < 16) {
        float m = -1e30f;
        #pragma unroll
        for (int i = 0; i < 16; ++i) m = fmaxf(m, lg[i]);
        float s = 0.f;
        #pragma unroll
        for (int i = 0; i < 16; ++i) s += expf(lg[i] - m);
        out[b * 16 + tid] = lg[tid] - m - logf(s);
    }
}

extern "C" void kernel_launch(void* const* d_in, const int* in_sizes, int n_in,
                              void* d_out, int out_size, void* d_ws, size_t ws_size,
                              hipStream_t stream) {
    static const int LFEAT[11] = {8, 32, 64, 64, 64, 128, 256, 512, 512, 512, 1024};
    static const int LDIM[11]  = {2048, 1024, 512, 256, 128, 64, 32, 16, 8, 4, 2};
    static const int LCIN[11]  = {3, 8, 32, 64, 64, 64, 128, 256, 512, 512, 512};

    const float* x = (const float*)d_in[0];
    const int B = in_sizes[0] / (3 * 2048);   // 512

    const size_t slot = (size_t)B * 32 * 512;   // floats
    float* bufA = (float*)d_ws;
    float* bufB = bufA + slot;
    unsigned short* wq = (unsigned short*)(bufB + slot);

    const float* W[11]; const float* bi[11]; const int* sl[11];
    for (int i = 0; i < 11; ++i) {
        W[i]  = (const float*)d_in[12 + 2 * i];
        bi[i] = (const float*)d_in[13 + 2 * i];
        sl[i] = (const int*)d_in[1 + i];
    }

    unsigned short* wqp[11];
    {
        size_t off = 0;
        for (int i = 2; i <= 10; ++i) {
            wqp[i] = wq + off;
            off += (size_t)3 * LFEAT[i] * LCIN[i];
        }
    }

    unsigned short* actA = (unsigned short*)bufA;
    unsigned short* actB = (unsigned short*)bufB;

    // W2..W5 -> bf16 (tiny; must precede chain)
    {
        WPrep wp;
        for (int i = 2; i <= 5; ++i) {
            wp.src[i - 2] = W[i];
            wp.dst[i - 2] = wqp[i];
            wp.n4[i - 2]  = (3 * LFEAT[i] * LCIN[i]) / 4;
        }
        wp.src[4] = nullptr; wp.dst[4] = nullptr; wp.n4[4] = 0;
        wprep25_kernel<<<64, 256, 0, stream>>>(wp);
    }

    // L0..L5 fused chain (+W6..W10 prep blocks): x -> actA [B,32,128]
    {
        WPrep wp;
        for (int i = 6; i <= 10; ++i) {
            wp.src[i - 6] = W[i];
            wp.dst[i - 6] = wqp[i];
            wp.n4[i - 6]  = (3 * LFEAT[i] * LCIN[i]) / 4;
        }
        chain_kernel<<<B + 256, 512, 0, stream>>>(
            x, W[0], bi[0], sl[0], W[1], bi[1], sl[1], actA,
            wqp[2], bi[2], sl[2], wqp[3], bi[3], sl[3],
            wqp[4], bi[4], sl[4], wqp[5], bi[5], sl[5],
            wp, B);
    }

    const int nbt32 = B / 32;   // 16
    const int nbt16 = B / 16;   // 32

    // L6..L8: BT=32 both-position staging
    {   dim3 g((LDIM[6]/2) * nbt32, LFEAT[6]/64);
        kdmfma2_kernel<128, 32><<<g, 256, 0, stream>>>(actA, wqp[6], bi[6], sl[6], actB, LFEAT[6], LDIM[6], nbt32); }
    {   dim3 g((LDIM[7]/2) * nbt32, LFEAT[7]/64);
        kdmfma2_kernel<256, 32><<<g, 256, 0, stream>>>(actB, wqp[7], bi[7], sl[7], actA, LFEAT[7], LDIM[7], nbt32); }
    {   dim3 g((LDIM[8]/2) * nbt32, LFEAT[8]/64);
        kdmfma2_kernel<512, 32><<<g, 256, 0, stream>>>(actA, wqp[8], bi[8], sl[8], actB, LFEAT[8], LDIM[8], nbt32); }

    // L9, L10: BT=16 (double the grid for overlap)
    {   dim3 g((LDIM[9]/2) * nbt16, LFEAT[9]/64);
        kdmfma2_kernel<512, 16><<<g, 256, 0, stream>>>(actB, wqp[9], bi[9], sl[9], actA, LFEAT[9], LDIM[9], nbt16); }
    {   dim3 g((LDIM[10]/2) * nbt16, LFEAT[10]/64);
        kdmfma2_kernel<512, 16><<<g, 256, 0, stream>>>(actA, wqp[10], bi[10], sl[10], actB, LFEAT[10], LDIM[10], nbt16); }

    // FC + log_softmax
    fc_lsm_kernel<<<B, 256, 0, stream>>>(actB, (const float*)d_in[34],
                                         (const float*)d_in[35], (float*)d_out);
}

// Round 8
// 83.858 us; speedup vs baseline: 1.0359x; 1.0359x over previous
//
#include <hip/hip_runtime.h>
#include <cstdint>
#include <cmath>

// ---------------------------------------------------------------------------
// KDNet: 11x fused { pointwise conv + ReLU + kd-gather + pair-maxpool }, then
// FC(1024->16) + log_softmax.  Multi-launch structure (cooperative grid.sync
// measured ~100us/sync on 8 XCDs — 6x worse; do not revisit).
//
//   e = 3d + sel[d]; q = e/dim; p = e%dim   (batch-uniform per position d)
//   pre[b,f,d] = dot(W[3f+q,:], x[b,:,p]) + bias[3f+q]
//   out[b,f,j] = relu(max(pre[.,.,2j], pre[.,.,2j+1]))
//
// History: r4 85.3 (T14 reg-prefetch chain); r5 82.3 BEST (l01 fused into
// chain, kdmfma2 for L8-L10); r6 86.7 / r7 86.9 REGRESSED — bundled
// {x-LDS staging, fp32-W-prefetch(spills), tail BT-halving}.  r7 proved the
// chain part recovered (42.5 -> <38.5) while totals stayed flat => the tail
// BT-halving (W-staging per output row doubled; staging-bound kernels) was
// the regression.  r8 = exact r5 restore + first-barrier skip in tail
// kernels (pure barrier removal, validated r6/r7).
//
// chain LDS pool 79872B (2 blk/CU):
//   qp tables @0..2048 persistent
//   IN @2048 (32K, dies after L2 A-loads)    W2 @34816 (12K, dies after L2)
//   W0s/b0s/W1s/b1s @47104 (3.8K, dies at B1)
//   O2 @47104 (32K, L2->L3)                  W3 @2048  (24K, over dead IN)
//   O3 @26624 (16K, L3->L4)                  W4 @47104 (24K, over dead O2)
//   O4 @71680 (8K, L4->L5)                   W5 @2048  (48K, over dead W3/O3)
//   O5 @51200 (8K, over dead W4)
// All W/O tiles XOR-slot-swizzled: byte ^= (row&SM)<<4.
// ---------------------------------------------------------------------------

typedef __attribute__((ext_vector_type(8))) short bhalf8;
typedef __attribute__((ext_vector_type(4))) float floatx4;

__device__ __forceinline__ unsigned short f2bf(float f) {
    uint32_t u = __float_as_uint(f);
    u += 0x7FFFu + ((u >> 16) & 1u);          // round-to-nearest-even
    return (unsigned short)(u >> 16);
}
__device__ __forceinline__ float bf2f(unsigned short u) {
    return __uint_as_float(((uint32_t)u) << 16);
}

struct WPrep {
    const float* src[5];
    unsigned short* dst[5];
    int n4[5];
};

// ---- W2..W5 fp32 -> bf16 linear (tiny; must precede chain) ----
__global__ __launch_bounds__(256)
void wprep25_kernel(WPrep wp) {
    const int stride = gridDim.x * 256;
    const int g0 = blockIdx.x * 256 + threadIdx.x;
    #pragma unroll
    for (int l = 0; l < 4; ++l) {
        const float4* s = reinterpret_cast<const float4*>(wp.src[l]);
        uint2* d = reinterpret_cast<uint2*>(wp.dst[l]);
        for (int i = g0; i < wp.n4[l]; i += stride) {
            const float4 v = s[i];
            uint2 o;
            o.x = (uint32_t)f2bf(v.x) | ((uint32_t)f2bf(v.y) << 16);
            o.y = (uint32_t)f2bf(v.z) | ((uint32_t)f2bf(v.w) << 16);
            d[i] = o;
        }
    }
}

template<int RB>
__device__ __forceinline__ int swaddr(int row, int colbyte) {
    constexpr int SM = (RB / 16 >= 8) ? 7 : (RB / 16 - 1);
    return row * RB + (colbyte ^ ((row & SM) << 4));
}

// 16B-granule index -> swizzled byte offset for a tile with CIN elems/row
template<int CIN>
__device__ __forceinline__ int wswz(int i) {
    constexpr int GPR = CIN / 8;          // granules per row
    constexpr int RB  = CIN * 2;
    const int row = i / GPR, c = i - row * GPR;
    return swaddr<RB>(row, c * 16);
}

template<int DIM, int CIN, int FEAT>
__device__ __forceinline__ void kdlayer(char* pool, int offIn, int offOut,
                                        int qpOff, int offW,
                                        const float* __restrict__ bg, int tid) {
    constexpr int NH  = CIN / 32;      // mfma k-slices
    constexpr int MT  = DIM / 16;      // M tiles (gathered rows)
    constexpr int NT  = FEAT / 16;     // N tiles
    constexpr int RBW = CIN * 2;       // row bytes, input + weight tiles
    constexpr int RBO = FEAT * 2;      // row bytes, output tile
    constexpr int WM  = (MT < 8) ? MT : 8;   // waves over M
    constexpr int WN  = 8 / WM;              // waves over N
    constexpr int MPW = MT / WM;             // M tiles per wave
    constexpr int NPW = NT / WN;             // N tiles per wave

    const unsigned short* qp = (const unsigned short*)(pool + qpOff);
    const int wv = tid >> 6, ln = tid & 63;
    const int g = ln >> 4, l15 = ln & 15;
    const int wm = wv % WM, wn = wv / WM;

    // A-frags + q-codes for this wave's M tiles
    bhalf8 aC[MPW][NH];
    uint32_t qpk[MPW];                 // 4x4-bit q per acc row
    #pragma unroll
    for (int i = 0; i < MPW; ++i) {
        const int mt = wm + i * WM;
        const int pa = qp[mt * 16 + l15] & 0xFFF;
        #pragma unroll
        for (int ks = 0; ks < NH; ++ks)
            aC[i][ks] = *(const bhalf8*)(pool + offIn +
                          swaddr<RBW>(pa, (ks * 32 + g * 8) * 2));
        const ushort4 qq = *(const ushort4*)(qp + mt * 16 + g * 4);
        qpk[i] = (uint32_t)(qq.x >> 12) | ((uint32_t)(qq.y >> 12) << 4)
               | ((uint32_t)(qq.z >> 12) << 8) | ((uint32_t)(qq.w >> 12) << 12);
    }

    #pragma unroll
    for (int ntj = 0; ntj < NPW; ++ntj) {
        const int nt = wn * NPW + ntj;
        const int f = nt * 16 + l15;
        bhalf8 bF[3][NH];              // B frags from LDS, once per nt
        #pragma unroll
        for (int q = 0; q < 3; ++q)
            #pragma unroll
            for (int ks = 0; ks < NH; ++ks)
                bF[q][ks] = *(const bhalf8*)(pool + offW +
                              swaddr<RBW>(3 * f + q, (ks * 32 + g * 8) * 2));
        const float bv0 = bg[3 * f + 0];
        const float bv1 = bg[3 * f + 1];
        const float bv2 = bg[3 * f + 2];
        #pragma unroll
        for (int i = 0; i < MPW; ++i) {
            floatx4 a0 = (floatx4){0.f,0.f,0.f,0.f};
            floatx4 a1 = (floatx4){0.f,0.f,0.f,0.f};
            floatx4 a2 = (floatx4){0.f,0.f,0.f,0.f};
            #pragma unroll
            for (int ks = 0; ks < NH; ++ks) {
                a0 = __builtin_amdgcn_mfma_f32_16x16x32_bf16(aC[i][ks], bF[0][ks], a0, 0, 0, 0);
                a1 = __builtin_amdgcn_mfma_f32_16x16x32_bf16(aC[i][ks], bF[1][ks], a1, 0, 0, 0);
                a2 = __builtin_amdgcn_mfma_f32_16x16x32_bf16(aC[i][ks], bF[2][ks], a2, 0, 0, 0);
            }
            const int mt = wm + i * WM;
            const int j0 = mt * 8 + g * 2;     // output row pair base
            float v[4];
            #pragma unroll
            for (int r = 0; r < 4; ++r) {
                const int qi = (qpk[i] >> (4 * r)) & 0xF;
                const float pre = (qi == 0) ? a0[r] : (qi == 1 ? a1[r] : a2[r]);
                const float bq  = (qi == 0) ? bv0  : (qi == 1 ? bv1  : bv2);
                v[r] = pre + bq;
            }
            *(unsigned short*)(pool + offOut + swaddr<RBO>(j0,     f * 2)) =
                f2bf(fmaxf(fmaxf(v[0], v[1]), 0.f));
            *(unsigned short*)(pool + offOut + swaddr<RBO>(j0 + 1, f * 2)) =
                f2bf(fmaxf(fmaxf(v[2], v[3]), 0.f));
        }
    }
}

__global__ __launch_bounds__(512, 4)
void chain_kernel(const float* __restrict__ x,                 // [B,3,2048]
                  const float* __restrict__ W0, const float* __restrict__ b0f,
                  const int* __restrict__ sel0,
                  const float* __restrict__ W1, const float* __restrict__ b1f,
                  const int* __restrict__ sel1,
                  unsigned short* __restrict__ outp,           // [B,32,128]
                  const unsigned short* __restrict__ w2, const float* __restrict__ b2, const int* __restrict__ s2,
                  const unsigned short* __restrict__ w3, const float* __restrict__ b3, const int* __restrict__ s3,
                  const unsigned short* __restrict__ w4, const float* __restrict__ b4, const int* __restrict__ s4,
                  const unsigned short* __restrict__ w5, const float* __restrict__ b5, const int* __restrict__ s5,
                  WPrep wp, int nrows) {
    const int tid = threadIdx.x;

    if ((int)blockIdx.x >= nrows) {            // ---- W6..W10 prep blocks ----
        const int stride = (gridDim.x - nrows) * 512;
        const int g0 = (blockIdx.x - nrows) * 512 + tid;
        #pragma unroll
        for (int l = 0; l < 5; ++l) {
            const float4* s = reinterpret_cast<const float4*>(wp.src[l]);
            uint2* d = reinterpret_cast<uint2*>(wp.dst[l]);
            for (int i = g0; i < wp.n4[l]; i += stride) {
                const float4 v = s[i];
                uint2 o;
                o.x = (uint32_t)f2bf(v.x) | ((uint32_t)f2bf(v.y) << 16);
                o.y = (uint32_t)f2bf(v.z) | ((uint32_t)f2bf(v.w) << 16);
                d[i] = o;
            }
        }
        return;
    }

    __shared__ __align__(16) char pool[79872];
    const int b = blockIdx.x;

    // ---- early prefetches (consumed later; hide global latency) ----
    bhalf8 w3r[3];
    #pragma unroll
    for (int u = 0; u < 3; ++u)
        w3r[u] = ((const bhalf8*)w3)[u * 512 + tid];
    bhalf8 w2r[2];
    w2r[0] = ((const bhalf8*)w2)[tid];
    if (tid < 256) w2r[1] = ((const bhalf8*)w2)[512 + tid];

    // ---- stage L0/L1 weights (temp @47104, dies at B1) + qp tables ----
    float* W0s = (float*)(pool + 47104);       // [24][3]
    float* b0s = W0s + 72;                     // [24]
    float* W1s = b0s + 24;                     // [96][8]
    float* b1s = W1s + 768;                    // [96]
    if (tid < 24) {
        W0s[tid * 3 + 0] = W0[tid * 3 + 0];
        W0s[tid * 3 + 1] = W0[tid * 3 + 1];
        W0s[tid * 3 + 2] = W0[tid * 3 + 2];
        b0s[tid] = b0f[tid];
    }
    if (tid < 96) {
        #pragma unroll
        for (int k = 0; k < 8; ++k) W1s[tid * 8 + k] = W1[tid * 8 + k];
        b1s[tid] = b1f[tid];
    }
    {
        unsigned short* qp2 = (unsigned short*)(pool + 0);
        unsigned short* qp3 = (unsigned short*)(pool + 1024);
        unsigned short* qp4 = (unsigned short*)(pool + 1536);
        unsigned short* qp5 = (unsigned short*)(pool + 1792);
        { const int d = tid;
          const int e = 3 * d + s2[d];
          const int q = (e >= 512) + (e >= 1024);
          qp2[d] = (unsigned short)((q << 12) | (e - q * 512)); }
        if (tid < 256) { const int d = tid;
          const int e = 3 * d + s3[d];
          const int q = (e >= 256) + (e >= 512);
          qp3[d] = (unsigned short)((q << 12) | (e - q * 256)); }
        if (tid < 128) { const int d = tid;
          const int e = 3 * d + s4[d];
          const int q = (e >= 128) + (e >= 256);
          qp4[d] = (unsigned short)((q << 12) | (e - q * 128)); }
        if (tid < 64)  { const int d = tid;
          const int e = 3 * d + s5[d];
          const int q = (e >= 64) + (e >= 128);
          qp5[d] = (unsigned short)((q << 12) | (e - q * 64)); }
    }
    __syncthreads();                                   // B0: W0s/W1s/qp ready

    // ---- fused L0+L1 for row b, position j1 = tid -> IN tile @2048 ----
    {
        const int j1 = tid;
        const float* xb = x + (size_t)b * 3 * 2048;

        float cols[2][8];
        int q1v[2];
        #pragma unroll
        for (int pos1 = 0; pos1 < 2; ++pos1) {
            const int d1 = 2 * j1 + pos1;
            const int e1 = 3 * d1 + sel1[d1];
            const int q1 = (e1 >= 1024) + (e1 >= 2048);
            const int p1 = e1 - q1 * 1024;
            q1v[pos1] = q1;

            float xv[2][3]; int qq0[2];
            #pragma unroll
            for (int pos0 = 0; pos0 < 2; ++pos0) {
                const int d0 = 2 * p1 + pos0;
                const int e0 = 3 * d0 + sel0[d0];
                const int q0 = (e0 >= 2048) + (e0 >= 4096);
                const int p0 = e0 - q0 * 2048;
                qq0[pos0] = q0;
                xv[pos0][0] = xb[p0];
                xv[pos0][1] = xb[2048 + p0];
                xv[pos0][2] = xb[4096 + p0];
            }
            #pragma unroll
            for (int f = 0; f < 8; ++f) {
                const int r0 = 3 * f + qq0[0], r1 = 3 * f + qq0[1];
                const float v0 = b0s[r0] + W0s[r0*3+0]*xv[0][0] + W0s[r0*3+1]*xv[0][1] + W0s[r0*3+2]*xv[0][2];
                const float v1 = b0s[r1] + W0s[r1*3+0]*xv[1][0] + W0s[r1*3+1]*xv[1][1] + W0s[r1*3+2]*xv[1][2];
                cols[pos1][f] = fmaxf(fmaxf(v0, v1), 0.f);
            }
        }
        #pragma unroll
        for (int gi = 0; gi < 4; ++gi) {
            bhalf8 og;
            #pragma unroll
            for (int fk = 0; fk < 8; ++fk) {
                const int f = gi * 8 + fk;
                const int r0 = 3 * f + q1v[0], r1 = 3 * f + q1v[1];
                float v0 = b1s[r0], v1 = b1s[r1];
                #pragma unroll
                for (int k = 0; k < 8; ++k) {
                    v0 = fmaf(cols[0][k], W1s[r0*8+k], v0);
                    v1 = fmaf(cols[1][k], W1s[r1*8+k], v1);
                }
                og[fk] = (short)f2bf(fmaxf(fmaxf(v0, v1), 0.f));
            }
            *(bhalf8*)(pool + 2048 + swaddr<64>(j1, gi * 16)) = og;
        }
    }
    // W2 -> LDS (swizzled)
    *(bhalf8*)(pool + 34816 + wswz<32>(tid)) = w2r[0];
    if (tid < 256)
        *(bhalf8*)(pool + 34816 + wswz<32>(512 + tid)) = w2r[1];
    __syncthreads();                                   // B1: IN + W2 ready

    kdlayer<512, 32, 64>(pool, 2048, 47104, 0, 34816, b2, tid);
    __syncthreads();                                   // B2: O2 ready, IN dead

    // W3 -> LDS (over dead IN); prefetch W4
    bhalf8 w4r[3];
    #pragma unroll
    for (int u = 0; u < 3; ++u)
        w4r[u] = ((const bhalf8*)w4)[u * 512 + tid];
    #pragma unroll
    for (int u = 0; u < 3; ++u)
        *(bhalf8*)(pool + 2048 + wswz<64>(u * 512 + tid)) = w3r[u];
    __syncthreads();                                   // B3: W3 visible

    kdlayer<256, 64, 64>(pool, 47104, 26624, 1024, 2048, b3, tid);
    __syncthreads();                                   // B4: O3 ready, O2/W3 dead

    // W4 -> LDS (over dead O2); prefetch W5
    bhalf8 w5r[6];
    #pragma unroll
    for (int u = 0; u < 6; ++u)
        w5r[u] = ((const bhalf8*)w5)[u * 512 + tid];
    #pragma unroll
    for (int u = 0; u < 3; ++u)
        *(bhalf8*)(pool + 47104 + wswz<64>(u * 512 + tid)) = w4r[u];
    __syncthreads();                                   // B5: W4 visible

    kdlayer<128, 64, 64>(pool, 26624, 71680, 1536, 47104, b4, tid);
    __syncthreads();                                   // B6: O4 ready, O3/W4 dead

    // W5 -> LDS (over dead W3/O3)
    #pragma unroll
    for (int u = 0; u < 6; ++u)
        *(bhalf8*)(pool + 2048 + wswz<64>(u * 512 + tid)) = w5r[u];
    __syncthreads();                                   // B7: W5 visible

    kdlayer<64, 64, 128>(pool, 71680, 51200, 1792, 2048, b5, tid);
    __syncthreads();                                   // B8: O5 ready

    // write out O5 [32][128] bf16: unswizzle on read, coalesced global store
    {
        char* dst = (char*)(outp + (size_t)b * 32 * 128);
        const int off = tid * 16;
        const bhalf8 v = *(const bhalf8*)(pool + 51200 +
                                          swaddr<256>(off >> 8, off & 255));
        *(bhalf8*)(dst + off) = v;
    }
}

// ---------------------------------------------------------------------------
// Unified bf16 MFMA GEMM layer, single-position staging (L6, L7).
// Tile: BT rows x 64 feats. KS = min(CIN,128).  First barrier skipped
// (pp==0 && k0==0: nothing to protect).
// ---------------------------------------------------------------------------
template<int CIN, int BT>
__global__ __launch_bounds__(256)
void kdmfma_kernel(const unsigned short* __restrict__ act,
                   const unsigned short* __restrict__ Wq,
                   const float* __restrict__ bias,
                   const int*   __restrict__ sel,
                   unsigned short* __restrict__ out,
                   int feat, int dim, int nbt) {
    constexpr int KS  = (CIN >= 128) ? 128 : CIN;
    constexpr int NH  = KS / 32;              // mfma k-slices per stage
    constexpr int LDK = KS + 8;
    constexpr int TPA = 256 / BT;             // threads per A row
    constexpr int EA  = KS / TPA;             // A elems per thread (mult of 8)
    constexpr int NSA = EA / 8;               // bhalf8 per thread (A)
    constexpr int NSW = KS / 32;              // bhalf8 per thread (W, 64 rows)
    constexpr int MF  = 2;                    // frag rows per wave
    constexpr int NF  = (BT == 64) ? 2 : 1;   // frag cols per wave
    __shared__ __align__(16) unsigned short Ab[BT][LDK];
    __shared__ __align__(16) unsigned short Wb[64][LDK];

    const int dimh = dim >> 1;
    const int bt = blockIdx.x % nbt;
    const int j  = blockIdx.x / nbt;
    const int f0 = blockIdx.y * 64;
    const int b0 = bt * BT;

    const int tid  = threadIdx.x;
    const int lane = tid & 63;
    const int wave = tid >> 6;

    const int srowA = tid / TPA;
    const int kgA   = (tid % TPA) * EA;
    const int srowW = tid >> 2;
    const int kgW   = (tid & 3) * (KS / 4);

    const int rowBase = (BT == 64) ? (wave & 1) * 32 : 0;
    const int colBase = (BT == 64) ? (wave >> 1) * 32 : wave * 16;

    floatx4 acc[2][MF][NF];
    #pragma unroll
    for (int pp = 0; pp < 2; ++pp)
        #pragma unroll
        for (int mi = 0; mi < MF; ++mi)
            #pragma unroll
            for (int ni = 0; ni < NF; ++ni)
                acc[pp][mi][ni] = (floatx4){0.f, 0.f, 0.f, 0.f};
    int qv[2];

    #pragma unroll
    for (int pp = 0; pp < 2; ++pp) {
        const int d = 2 * j + pp;
        const int s = sel[d];
        const int e = 3 * d + s;
        const int q = (e >= dim) + (e >= 2 * dim);
        const int p = e - q * dim;
        qv[pp] = q;

        const unsigned short* Ap = act + ((size_t)(b0 + srowA) * dim + p) * CIN + kgA;
        const unsigned short* Wp = Wq + ((size_t)(3 * (f0 + srowW) + q)) * CIN + kgW;

        bhalf8 pa[NSA], pw[NSW];
        #pragma unroll
        for (int u = 0; u < NSA; ++u)
            pa[u] = *reinterpret_cast<const bhalf8*>(Ap + u * 8);
        #pragma unroll
        for (int u = 0; u < NSW; ++u)
            pw[u] = *reinterpret_cast<const bhalf8*>(Wp + u * 8);

        for (int k0 = 0; k0 < CIN; k0 += KS) {
            if (pp || k0) __syncthreads();   // prior stage's reads complete
            #pragma unroll
            for (int u = 0; u < NSA; ++u)
                *reinterpret_cast<bhalf8*>(&Ab[srowA][kgA + u * 8]) = pa[u];
            #pragma unroll
            for (int u = 0; u < NSW; ++u)
                *reinterpret_cast<bhalf8*>(&Wb[srowW][kgW + u * 8]) = pw[u];
            if (k0 + KS < CIN) {   // prefetch next stage
                #pragma unroll
                for (int u = 0; u < NSA; ++u)
                    pa[u] = *reinterpret_cast<const bhalf8*>(Ap + k0 + KS + u * 8);
                #pragma unroll
                for (int u = 0; u < NSW; ++u)
                    pw[u] = *reinterpret_cast<const bhalf8*>(Wp + k0 + KS + u * 8);
            }
            __syncthreads();

            #pragma unroll
            for (int ks = 0; ks < NH; ++ks) {
                const int kk = ks * 32 + (lane >> 4) * 8;
                bhalf8 aF[MF], bF[NF];
                #pragma unroll
                for (int mi = 0; mi < MF; ++mi)
                    aF[mi] = *reinterpret_cast<const bhalf8*>(
                        &Ab[rowBase + mi * 16 + (lane & 15)][kk]);
                #pragma unroll
                for (int ni = 0; ni < NF; ++ni)
                    bF[ni] = *reinterpret_cast<const bhalf8*>(
                        &Wb[colBase + ni * 16 + (lane & 15)][kk]);
                #pragma unroll
                for (int mi = 0; mi < MF; ++mi)
                    #pragma unroll
                    for (int ni = 0; ni < NF; ++ni)
                        acc[pp][mi][ni] = __builtin_amdgcn_mfma_f32_16x16x32_bf16(
                            aF[mi], bF[ni], acc[pp][mi][ni], 0, 0, 0);
            }
        }
    }

    const int orow = (lane >> 4) << 2;
    const int ocol = lane & 15;
    #pragma unroll
    for (int mi = 0; mi < MF; ++mi)
        #pragma unroll
        for (int ni = 0; ni < NF; ++ni) {
            const int fc = f0 + colBase + ni * 16 + ocol;
            const float bv0 = bias[3 * fc + qv[0]];
            const float bv1 = bias[3 * fc + qv[1]];
            #pragma unroll
            for (int i = 0; i < 4; ++i) {
                const int br = b0 + rowBase + mi * 16 + orow + i;
                const float v = fmaxf(fmaxf(acc[0][mi][ni][i] + bv0,
                                            acc[1][mi][ni][i] + bv1), 0.f);
                out[((size_t)br * dimh + j) * feat + fc] = f2bf(v);
            }
        }
}

// ---------------------------------------------------------------------------
// kdmfma2: CIN=512 tail (L8..L10), BT=32.  Stages BOTH positions per k-stage
// (Ab[2]/Wb[2], 52KB LDS -> 3 blk/CU): barrier pairs 8 -> 4 (first skipped).
// Per-acc k-slice order identical to kdmfma (bitwise same results).
// ---------------------------------------------------------------------------
template<int CIN, int BT>
__global__ __launch_bounds__(256)
void kdmfma2_kernel(const unsigned short* __restrict__ act,
                    const unsigned short* __restrict__ Wq,
                    const float* __restrict__ bias,
                    const int*   __restrict__ sel,
                    unsigned short* __restrict__ out,
                    int feat, int dim, int nbt) {
    constexpr int KS  = 128;
    constexpr int NH  = KS / 32;              // 4
    constexpr int LDK = KS + 8;
    constexpr int TPA = 256 / BT;             // 8
    constexpr int EA  = KS / TPA;             // 16
    constexpr int NSA = EA / 8;               // 2
    constexpr int NSW = KS / 32;              // 4
    constexpr int MF  = 2;
    __shared__ __align__(16) unsigned short Ab[2][BT][LDK];
    __shared__ __align__(16) unsigned short Wb[2][64][LDK];

    const int dimh = dim >> 1;
    const int bt = blockIdx.x % nbt;
    const int j  = blockIdx.x / nbt;
    const int f0 = blockIdx.y * 64;
    const int b0 = bt * BT;

    const int tid  = threadIdx.x;
    const int lane = tid & 63;
    const int wave = tid >> 6;

    const int srowA = tid / TPA;
    const int kgA   = (tid % TPA) * EA;
    const int srowW = tid >> 2;
    const int kgW   = (tid & 3) * (KS / 4);
    const int colBase = wave * 16;

    int qv[2];
    const unsigned short* Ap[2];
    const unsigned short* Wp[2];
    #pragma unroll
    for (int pp = 0; pp < 2; ++pp) {
        const int d = 2 * j + pp;
        const int e = 3 * d + sel[d];
        const int q = (e >= dim) + (e >= 2 * dim);
        const int p = e - q * dim;
        qv[pp] = q;
        Ap[pp] = act + ((size_t)(b0 + srowA) * dim + p) * CIN + kgA;
        Wp[pp] = Wq + ((size_t)(3 * (f0 + srowW) + q)) * CIN + kgW;
    }

    floatx4 acc[2][MF];
    #pragma unroll
    for (int pp = 0; pp < 2; ++pp)
        #pragma unroll
        for (int mi = 0; mi < MF; ++mi)
            acc[pp][mi] = (floatx4){0.f, 0.f, 0.f, 0.f};

    bhalf8 pa[2][NSA], pw[2][NSW];
    #pragma unroll
    for (int pp = 0; pp < 2; ++pp) {
        #pragma unroll
        for (int u = 0; u < NSA; ++u)
            pa[pp][u] = *reinterpret_cast<const bhalf8*>(Ap[pp] + u * 8);
        #pragma unroll
        for (int u = 0; u < NSW; ++u)
            pw[pp][u] = *reinterpret_cast<const bhalf8*>(Wp[pp] + u * 8);
    }

    for (int k0 = 0; k0 < CIN; k0 += KS) {
        if (k0) __syncthreads();   // protect prior stage's fragment reads
        #pragma unroll
        for (int pp = 0; pp < 2; ++pp) {
            #pragma unroll
            for (int u = 0; u < NSA; ++u)
                *reinterpret_cast<bhalf8*>(&Ab[pp][srowA][kgA + u * 8]) = pa[pp][u];
            #pragma unroll
            for (int u = 0; u < NSW; ++u)
                *reinterpret_cast<bhalf8*>(&Wb[pp][srowW][kgW + u * 8]) = pw[pp][u];
        }
        if (k0 + KS < CIN) {
            #pragma unroll
            for (int pp = 0; pp < 2; ++pp) {
                #pragma unroll
                for (int u = 0; u < NSA; ++u)
                    pa[pp][u] = *reinterpret_cast<const bhalf8*>(Ap[pp] + k0 + KS + u * 8);
                #pragma unroll
                for (int u = 0; u < NSW; ++u)
                    pw[pp][u] = *reinterpret_cast<const bhalf8*>(Wp[pp] + k0 + KS + u * 8);
            }
        }
        __syncthreads();

        #pragma unroll
        for (int ks = 0; ks < NH; ++ks) {
            const int kk = ks * 32 + (lane >> 4) * 8;
            bhalf8 aF[2][MF], bF[2];
            #pragma unroll
            for (int pp = 0; pp < 2; ++pp) {
                #pragma unroll
                for (int mi = 0; mi < MF; ++mi)
                    aF[pp][mi] = *reinterpret_cast<const bhalf8*>(
                        &Ab[pp][mi * 16 + (lane & 15)][kk]);
                bF[pp] = *reinterpret_cast<const bhalf8*>(
                        &Wb[pp][colBase + (lane & 15)][kk]);
            }
            #pragma unroll
            for (int pp = 0; pp < 2; ++pp)
                #pragma unroll
                for (int mi = 0; mi < MF; ++mi)
                    acc[pp][mi] = __builtin_amdgcn_mfma_f32_16x16x32_bf16(
                        aF[pp][mi], bF[pp], acc[pp][mi], 0, 0, 0);
        }
    }

    const int orow = (lane >> 4) << 2;
    const int ocol = lane & 15;
    #pragma unroll
    for (int mi = 0; mi < MF; ++mi) {
        const int fc = f0 + colBase + ocol;
        const float bv0 = bias[3 * fc + qv[0]];
        const float bv1 = bias[3 * fc + qv[1]];
        #pragma unroll
        for (int i = 0; i < 4; ++i) {
            const int br = b0 + mi * 16 + orow + i;
            const float v = fmaxf(fmaxf(acc[0][mi][i] + bv0,
                                        acc[1][mi][i] + bv1), 0.f);
            out[((size_t)br * dimh + j) * feat + fc] = f2bf(v);
        }
    }
}

// FC (1024 -> 16) + log_softmax; input bf16 [B, 1024].
__global__ __launch_bounds__(256)
void fc_lsm_kernel(const unsigned short* __restrict__ y,
                   const float* __restrict__ Wfc,
                   const float* __restrict__ bfc,
                   float* __restrict__ out) {
    const int b   = blockIdx.x;
    const int tid = threadIdx.x;
    __shared__ __align__(16) float ys[1024];
    __shared__ float lg[16];

    {
        const ushort4 v = reinterpret_cast<const ushort4*>(y + (size_t)b * 1024)[tid];
        ys[tid * 4 + 0] = bf2f(v.x);
        ys[tid * 4 + 1] = bf2f(v.y);
        ys[tid * 4 + 2] = bf2f(v.z);
        ys[tid * 4 + 3] = bf2f(v.w);
    }
    __syncthreads();

    const int l = tid >> 4, lane = tid & 15;
    const float4* w4 = reinterpret_cast<const float4*>(Wfc + (size_t)l * 1024);
    const float4* y4 = reinterpret_cast<const float4*>(ys);
    float p = 0.f;
    #pragma unroll
    for (int i = 0; i < 16; ++i) {
        const float4 a = y4[lane + 16 * i];
        const float4 w = w4[lane + 16 * i];
        p += a.x * w.x + a.y * w.y + a.z * w.z + a.w * w.w;
    }
    #pragma unroll
    for (int off = 8; off > 0; off >>= 1) p += __shfl_down(p, off, 16);
    if (lane == 0) lg[l] = p + bfc[l];
    __syncthreads();

    if (tid < 16) {
        float m = -1e30f;
        #pragma unroll
        for (int i = 0; i < 16; ++i) m = fmaxf(m, lg[i]);
        float s = 0.f;
        #pragma unroll
        for (int i = 0; i < 16; ++i) s += expf(lg[i] - m);
        out[b * 16 + tid] = lg[tid] - m - logf(s);
    }
}

extern "C" void kernel_launch(void* const* d_in, const int* in_sizes, int n_in,
                              void* d_out, int out_size, void* d_ws, size_t ws_size,
                              hipStream_t stream) {
    static const int LFEAT[11] = {8, 32, 64, 64, 64, 128, 256, 512, 512, 512, 1024};
    static const int LDIM[11]  = {2048, 1024, 512, 256, 128, 64, 32, 16, 8, 4, 2};
    static const int LCIN[11]  = {3, 8, 32, 64, 64, 64, 128, 256, 512, 512, 512};

    const float* x = (const float*)d_in[0];
    const int B = in_sizes[0] / (3 * 2048);   // 512

    const size_t slot = (size_t)B * 32 * 512;   // floats
    float* bufA = (float*)d_ws;
    float* bufB = bufA + slot;
    unsigned short* wq = (unsigned short*)(bufB + slot);

    const float* W[11]; const float* bi[11]; const int* sl[11];
    for (int i = 0; i < 11; ++i) {
        W[i]  = (const float*)d_in[12 + 2 * i];
        bi[i] = (const float*)d_in[13 + 2 * i];
        sl[i] = (const int*)d_in[1 + i];
    }

    unsigned short* wqp[11];
    {
        size_t off = 0;
        for (int i = 2; i <= 10; ++i) {
            wqp[i] = wq + off;
            off += (size_t)3 * LFEAT[i] * LCIN[i];
        }
    }

    unsigned short* actA = (unsigned short*)bufA;
    unsigned short* actB = (unsigned short*)bufB;

    // W2..W5 -> bf16 (tiny; must precede chain)
    {
        WPrep wp;
        for (int i = 2; i <= 5; ++i) {
            wp.src[i - 2] = W[i];
            wp.dst[i - 2] = wqp[i];
            wp.n4[i - 2]  = (3 * LFEAT[i] * LCIN[i]) / 4;
        }
        wp.src[4] = nullptr; wp.dst[4] = nullptr; wp.n4[4] = 0;
        wprep25_kernel<<<64, 256, 0, stream>>>(wp);
    }

    // L0..L5 fused chain (+W6..W10 prep blocks): x -> actA [B,32,128]
    {
        WPrep wp;
        for (int i = 6; i <= 10; ++i) {
            wp.src[i - 6] = W[i];
            wp.dst[i - 6] = wqp[i];
            wp.n4[i - 6]  = (3 * LFEAT[i] * LCIN[i]) / 4;
        }
        chain_kernel<<<B + 256, 512, 0, stream>>>(
            x, W[0], bi[0], sl[0], W[1], bi[1], sl[1], actA,
            wqp[2], bi[2], sl[2], wqp[3], bi[3], sl[3],
            wqp[4], bi[4], sl[4], wqp[5], bi[5], sl[5],
            wp, B);
    }

    const int nbt64 = B / 64;   // 8
    const int nbt32 = B / 32;   // 16

    // L6, L7: BT=64 single-position staging
    {   dim3 g((LDIM[6]/2) * nbt64, LFEAT[6]/64);
        kdmfma_kernel<128, 64><<<g, 256, 0, stream>>>(actA, wqp[6], bi[6], sl[6], actB, LFEAT[6], LDIM[6], nbt64); }
    {   dim3 g((LDIM[7]/2) * nbt64, LFEAT[7]/64);
        kdmfma_kernel<256, 64><<<g, 256, 0, stream>>>(actB, wqp[7], bi[7], sl[7], actA, LFEAT[7], LDIM[7], nbt64); }

    // L8..L10: BT=32 both-position staging (kdmfma2)
    {   dim3 g((LDIM[8]/2) * nbt32, LFEAT[8]/64);
        kdmfma2_kernel<512, 32><<<g, 256, 0, stream>>>(actA, wqp[8], bi[8], sl[8], actB, LFEAT[8], LDIM[8], nbt32); }
    {   dim3 g((LDIM[9]/2) * nbt32, LFEAT[9]/64);
        kdmfma2_kernel<512, 32><<<g, 256, 0, stream>>>(actB, wqp[9], bi[9], sl[9], actA, LFEAT[9], LDIM[9], nbt32); }
    {   dim3 g((LDIM[10]/2) * nbt32, LFEAT[10]/64);
        kdmfma2_kernel<512, 32><<<g, 256, 0, stream>>>(actA, wqp[10], bi[10], sl[10], actB, LFEAT[10], LDIM[10], nbt32); }

    // FC + log_softmax
    fc_lsm_kernel<<<B, 256, 0, stream>>>(actB, (const float*)d_in[34],
                                         (const float*)d_in[35], (float*)d_out);
}

// Round 9
// 81.858 us; speedup vs baseline: 1.0612x; 1.0244x over previous
//
#include <hip/hip_runtime.h>
#include <cstdint>
#include <cmath>

// ---------------------------------------------------------------------------
// KDNet: 11x fused { pointwise conv + ReLU + kd-gather + pair-maxpool }, then
// FC(1024->16) + log_softmax.  Multi-launch structure (cooperative grid.sync
// measured ~100us/sync on 8 XCDs — 6x worse; do not revisit).
//
//   e = 3d + sel[d]; q = e/dim; p = e%dim   (batch-uniform per position d)
//   pre[b,f,d] = dot(W[3f+q,:], x[b,:,p]) + bias[3f+q]
//   out[b,f,j] = relu(max(pre[.,.,2j], pre[.,.,2j+1]))
//
// History: r5 82.3 BEST / r8 83.9 (same config; noise band +-1.5us).
// r6/r7 86.7/86.9 regression isolated to tail BT-halving; fp32-W-prefetch
// spills (r6) fixed by bf16 prefetch.  r9 = r8 + the ONE untested r6
// component, isolated: x row -> LDS (3 coalesced float4/thr) + qp0 table,
// replacing L01's 12 scattered global x-loads + 4 scattered sel0 loads on
// the pre-B1 critical path.  Registers die at B0 (no cross-kdlayer hold ->
// no r6 spill mechanism).  LDS: xs@51200 (24K) + qp0@75776 (4K), both die
// at B1, alias regions first written at B5/B7.
//
// chain LDS pool 79872B (2 blk/CU):
//   qp tables @0..2048 persistent
//   IN @2048 (32K, dies after L2 A-loads)    W2 @34816 (12K, dies after L2)
//   W0s/b0s/W1s/b1s @47104 (3.8K, dies at B1)
//   xs @51200 (24K f32, dies at B1)          qp0 @75776 (4K, dies at B1)
//   O2 @47104 (32K, L2->L3)                  W3 @2048  (24K, over dead IN)
//   O3 @26624 (16K, L3->L4)                  W4 @47104 (24K, over dead O2)
//   O4 @71680 (8K, L4->L5)                   W5 @2048  (48K, over dead W3/O3)
//   O5 @51200 (8K, over dead W4/xs)
// All W/O tiles XOR-slot-swizzled: byte ^= (row&SM)<<4.
// ---------------------------------------------------------------------------

typedef __attribute__((ext_vector_type(8))) short bhalf8;
typedef __attribute__((ext_vector_type(4))) float floatx4;

__device__ __forceinline__ unsigned short f2bf(float f) {
    uint32_t u = __float_as_uint(f);
    u += 0x7FFFu + ((u >> 16) & 1u);          // round-to-nearest-even
    return (unsigned short)(u >> 16);
}
__device__ __forceinline__ float bf2f(unsigned short u) {
    return __uint_as_float(((uint32_t)u) << 16);
}

struct WPrep {
    const float* src[5];
    unsigned short* dst[5];
    int n4[5];
};

// ---- W2..W5 fp32 -> bf16 linear (tiny; must precede chain) ----
__global__ __launch_bounds__(256)
void wprep25_kernel(WPrep wp) {
    const int stride = gridDim.x * 256;
    const int g0 = blockIdx.x * 256 + threadIdx.x;
    #pragma unroll
    for (int l = 0; l < 4; ++l) {
        const float4* s = reinterpret_cast<const float4*>(wp.src[l]);
        uint2* d = reinterpret_cast<uint2*>(wp.dst[l]);
        for (int i = g0; i < wp.n4[l]; i += stride) {
            const float4 v = s[i];
            uint2 o;
            o.x = (uint32_t)f2bf(v.x) | ((uint32_t)f2bf(v.y) << 16);
            o.y = (uint32_t)f2bf(v.z) | ((uint32_t)f2bf(v.w) << 16);
            d[i] = o;
        }
    }
}

template<int RB>
__device__ __forceinline__ int swaddr(int row, int colbyte) {
    constexpr int SM = (RB / 16 >= 8) ? 7 : (RB / 16 - 1);
    return row * RB + (colbyte ^ ((row & SM) << 4));
}

// 16B-granule index -> swizzled byte offset for a tile with CIN elems/row
template<int CIN>
__device__ __forceinline__ int wswz(int i) {
    constexpr int GPR = CIN / 8;          // granules per row
    constexpr int RB  = CIN * 2;
    const int row = i / GPR, c = i - row * GPR;
    return swaddr<RB>(row, c * 16);
}

template<int DIM, int CIN, int FEAT>
__device__ __forceinline__ void kdlayer(char* pool, int offIn, int offOut,
                                        int qpOff, int offW,
                                        const float* __restrict__ bg, int tid) {
    constexpr int NH  = CIN / 32;      // mfma k-slices
    constexpr int MT  = DIM / 16;      // M tiles (gathered rows)
    constexpr int NT  = FEAT / 16;     // N tiles
    constexpr int RBW = CIN * 2;       // row bytes, input + weight tiles
    constexpr int RBO = FEAT * 2;      // row bytes, output tile
    constexpr int WM  = (MT < 8) ? MT : 8;   // waves over M
    constexpr int WN  = 8 / WM;              // waves over N
    constexpr int MPW = MT / WM;             // M tiles per wave
    constexpr int NPW = NT / WN;             // N tiles per wave

    const unsigned short* qp = (const unsigned short*)(pool + qpOff);
    const int wv = tid >> 6, ln = tid & 63;
    const int g = ln >> 4, l15 = ln & 15;
    const int wm = wv % WM, wn = wv / WM;

    // A-frags + q-codes for this wave's M tiles
    bhalf8 aC[MPW][NH];
    uint32_t qpk[MPW];                 // 4x4-bit q per acc row
    #pragma unroll
    for (int i = 0; i < MPW; ++i) {
        const int mt = wm + i * WM;
        const int pa = qp[mt * 16 + l15] & 0xFFF;
        #pragma unroll
        for (int ks = 0; ks < NH; ++ks)
            aC[i][ks] = *(const bhalf8*)(pool + offIn +
                          swaddr<RBW>(pa, (ks * 32 + g * 8) * 2));
        const ushort4 qq = *(const ushort4*)(qp + mt * 16 + g * 4);
        qpk[i] = (uint32_t)(qq.x >> 12) | ((uint32_t)(qq.y >> 12) << 4)
               | ((uint32_t)(qq.z >> 12) << 8) | ((uint32_t)(qq.w >> 12) << 12);
    }

    #pragma unroll
    for (int ntj = 0; ntj < NPW; ++ntj) {
        const int nt = wn * NPW + ntj;
        const int f = nt * 16 + l15;
        bhalf8 bF[3][NH];              // B frags from LDS, once per nt
        #pragma unroll
        for (int q = 0; q < 3; ++q)
            #pragma unroll
            for (int ks = 0; ks < NH; ++ks)
                bF[q][ks] = *(const bhalf8*)(pool + offW +
                              swaddr<RBW>(3 * f + q, (ks * 32 + g * 8) * 2));
        const float bv0 = bg[3 * f + 0];
        const float bv1 = bg[3 * f + 1];
        const float bv2 = bg[3 * f + 2];
        #pragma unroll
        for (int i = 0; i < MPW; ++i) {
            floatx4 a0 = (floatx4){0.f,0.f,0.f,0.f};
            floatx4 a1 = (floatx4){0.f,0.f,0.f,0.f};
            floatx4 a2 = (floatx4){0.f,0.f,0.f,0.f};
            #pragma unroll
            for (int ks = 0; ks < NH; ++ks) {
                a0 = __builtin_amdgcn_mfma_f32_16x16x32_bf16(aC[i][ks], bF[0][ks], a0, 0, 0, 0);
                a1 = __builtin_amdgcn_mfma_f32_16x16x32_bf16(aC[i][ks], bF[1][ks], a1, 0, 0, 0);
                a2 = __builtin_amdgcn_mfma_f32_16x16x32_bf16(aC[i][ks], bF[2][ks], a2, 0, 0, 0);
            }
            const int mt = wm + i * WM;
            const int j0 = mt * 8 + g * 2;     // output row pair base
            float v[4];
            #pragma unroll
            for (int r = 0; r < 4; ++r) {
                const int qi = (qpk[i] >> (4 * r)) & 0xF;
                const float pre = (qi == 0) ? a0[r] : (qi == 1 ? a1[r] : a2[r]);
                const float bq  = (qi == 0) ? bv0  : (qi == 1 ? bv1  : bv2);
                v[r] = pre + bq;
            }
            *(unsigned short*)(pool + offOut + swaddr<RBO>(j0,     f * 2)) =
                f2bf(fmaxf(fmaxf(v[0], v[1]), 0.f));
            *(unsigned short*)(pool + offOut + swaddr<RBO>(j0 + 1, f * 2)) =
                f2bf(fmaxf(fmaxf(v[2], v[3]), 0.f));
        }
    }
}

__global__ __launch_bounds__(512, 4)
void chain_kernel(const float* __restrict__ x,                 // [B,3,2048]
                  const float* __restrict__ W0, const float* __restrict__ b0f,
                  const int* __restrict__ sel0,
                  const float* __restrict__ W1, const float* __restrict__ b1f,
                  const int* __restrict__ sel1,
                  unsigned short* __restrict__ outp,           // [B,32,128]
                  const unsigned short* __restrict__ w2, const float* __restrict__ b2, const int* __restrict__ s2,
                  const unsigned short* __restrict__ w3, const float* __restrict__ b3, const int* __restrict__ s3,
                  const unsigned short* __restrict__ w4, const float* __restrict__ b4, const int* __restrict__ s4,
                  const unsigned short* __restrict__ w5, const float* __restrict__ b5, const int* __restrict__ s5,
                  WPrep wp, int nrows) {
    const int tid = threadIdx.x;

    if ((int)blockIdx.x >= nrows) {            // ---- W6..W10 prep blocks ----
        const int stride = (gridDim.x - nrows) * 512;
        const int g0 = (blockIdx.x - nrows) * 512 + tid;
        #pragma unroll
        for (int l = 0; l < 5; ++l) {
            const float4* s = reinterpret_cast<const float4*>(wp.src[l]);
            uint2* d = reinterpret_cast<uint2*>(wp.dst[l]);
            for (int i = g0; i < wp.n4[l]; i += stride) {
                const float4 v = s[i];
                uint2 o;
                o.x = (uint32_t)f2bf(v.x) | ((uint32_t)f2bf(v.y) << 16);
                o.y = (uint32_t)f2bf(v.z) | ((uint32_t)f2bf(v.w) << 16);
                d[i] = o;
            }
        }
        return;
    }

    __shared__ __align__(16) char pool[79872];
    const int b = blockIdx.x;

    // ---- earliest loads: x row (coalesced) + W2/W3 bf16 prefetch ----
    const float4* xg = (const float4*)(x + (size_t)b * 6144);
    const float4 xr0 = xg[tid], xr1 = xg[512 + tid], xr2 = xg[1024 + tid];

    bhalf8 w3r[3];
    #pragma unroll
    for (int u = 0; u < 3; ++u)
        w3r[u] = ((const bhalf8*)w3)[u * 512 + tid];
    bhalf8 w2r[2];
    w2r[0] = ((const bhalf8*)w2)[tid];
    if (tid < 256) w2r[1] = ((const bhalf8*)w2)[512 + tid];

    // ---- stage L0/L1 weights (temp @47104, dies at B1) + qp tables ----
    float* W0s = (float*)(pool + 47104);       // [24][3]
    float* b0s = W0s + 72;                     // [24]
    float* W1s = b0s + 24;                     // [96][8]
    float* b1s = W1s + 768;                    // [96]
    if (tid < 24) {
        W0s[tid * 3 + 0] = W0[tid * 3 + 0];
        W0s[tid * 3 + 1] = W0[tid * 3 + 1];
        W0s[tid * 3 + 2] = W0[tid * 3 + 2];
        b0s[tid] = b0f[tid];
    }
    if (tid < 96) {
        #pragma unroll
        for (int k = 0; k < 8; ++k) W1s[tid * 8 + k] = W1[tid * 8 + k];
        b1s[tid] = b1f[tid];
    }
    {
        unsigned short* qp2 = (unsigned short*)(pool + 0);
        unsigned short* qp3 = (unsigned short*)(pool + 1024);
        unsigned short* qp4 = (unsigned short*)(pool + 1536);
        unsigned short* qp5 = (unsigned short*)(pool + 1792);
        { const int d = tid;
          const int e = 3 * d + s2[d];
          const int q = (e >= 512) + (e >= 1024);
          qp2[d] = (unsigned short)((q << 12) | (e - q * 512)); }
        if (tid < 256) { const int d = tid;
          const int e = 3 * d + s3[d];
          const int q = (e >= 256) + (e >= 512);
          qp3[d] = (unsigned short)((q << 12) | (e - q * 256)); }
        if (tid < 128) { const int d = tid;
          const int e = 3 * d + s4[d];
          const int q = (e >= 128) + (e >= 256);
          qp4[d] = (unsigned short)((q << 12) | (e - q * 128)); }
        if (tid < 64)  { const int d = tid;
          const int e = 3 * d + s5[d];
          const int q = (e >= 64) + (e >= 128);
          qp5[d] = (unsigned short)((q << 12) | (e - q * 64)); }
        // qp0: sel0 -> (q<<12 | p), 2048 entries @75776 (dies at B1)
        unsigned short* qp0 = (unsigned short*)(pool + 75776);
        #pragma unroll
        for (int it = 0; it < 4; ++it) {
            const int d = it * 512 + tid;
            const int e = 3 * d + sel0[d];
            const int q = (e >= 2048) + (e >= 4096);
            qp0[d] = (unsigned short)((q << 12) | (e - q * 2048));
        }
    }
    // ---- x -> LDS (linear f32 @51200, dies at B1) ----
    {
        float4* xs4 = (float4*)(pool + 51200);
        xs4[tid] = xr0; xs4[512 + tid] = xr1; xs4[1024 + tid] = xr2;
    }
    __syncthreads();                                   // B0

    // ---- fused L0+L1 for row b, position j1 = tid -> IN tile @2048 ----
    {
        const int j1 = tid;
        const float* xs = (const float*)(pool + 51200);
        const unsigned short* qp0 = (const unsigned short*)(pool + 75776);

        float cols[2][8];
        int q1v[2];
        #pragma unroll
        for (int pos1 = 0; pos1 < 2; ++pos1) {
            const int d1 = 2 * j1 + pos1;
            const int e1 = 3 * d1 + sel1[d1];
            const int q1 = (e1 >= 1024) + (e1 >= 2048);
            const int p1 = e1 - q1 * 1024;
            q1v[pos1] = q1;

            float xv[2][3]; int qq0[2];
            #pragma unroll
            for (int pos0 = 0; pos0 < 2; ++pos0) {
                const int c0 = qp0[2 * p1 + pos0];
                const int q0 = c0 >> 12;
                const int p0 = c0 & 0xFFF;
                qq0[pos0] = q0;
                xv[pos0][0] = xs[p0];
                xv[pos0][1] = xs[2048 + p0];
                xv[pos0][2] = xs[4096 + p0];
            }
            #pragma unroll
            for (int f = 0; f < 8; ++f) {
                const int r0 = 3 * f + qq0[0], r1 = 3 * f + qq0[1];
                const float v0 = b0s[r0] + W0s[r0*3+0]*xv[0][0] + W0s[r0*3+1]*xv[0][1] + W0s[r0*3+2]*xv[0][2];
                const float v1 = b0s[r1] + W0s[r1*3+0]*xv[1][0] + W0s[r1*3+1]*xv[1][1] + W0s[r1*3+2]*xv[1][2];
                cols[pos1][f] = fmaxf(fmaxf(v0, v1), 0.f);
            }
        }
        #pragma unroll
        for (int gi = 0; gi < 4; ++gi) {
            bhalf8 og;
            #pragma unroll
            for (int fk = 0; fk < 8; ++fk) {
                const int f = gi * 8 + fk;
                const int r0 = 3 * f + q1v[0], r1 = 3 * f + q1v[1];
                float v0 = b1s[r0], v1 = b1s[r1];
                #pragma unroll
                for (int k = 0; k < 8; ++k) {
                    v0 = fmaf(cols[0][k], W1s[r0*8+k], v0);
                    v1 = fmaf(cols[1][k], W1s[r1*8+k], v1);
                }
                og[fk] = (short)f2bf(fmaxf(fmaxf(v0, v1), 0.f));
            }
            *(bhalf8*)(pool + 2048 + swaddr<64>(j1, gi * 16)) = og;
        }
    }
    // W2 -> LDS (swizzled)
    *(bhalf8*)(pool + 34816 + wswz<32>(tid)) = w2r[0];
    if (tid < 256)
        *(bhalf8*)(pool + 34816 + wswz<32>(512 + tid)) = w2r[1];
    __syncthreads();                                   // B1: IN + W2 ready

    kdlayer<512, 32, 64>(pool, 2048, 47104, 0, 34816, b2, tid);
    __syncthreads();                                   // B2: O2 ready, IN dead

    // W3 -> LDS (over dead IN); prefetch W4
    bhalf8 w4r[3];
    #pragma unroll
    for (int u = 0; u < 3; ++u)
        w4r[u] = ((const bhalf8*)w4)[u * 512 + tid];
    #pragma unroll
    for (int u = 0; u < 3; ++u)
        *(bhalf8*)(pool + 2048 + wswz<64>(u * 512 + tid)) = w3r[u];
    __syncthreads();                                   // B3: W3 visible

    kdlayer<256, 64, 64>(pool, 47104, 26624, 1024, 2048, b3, tid);
    __syncthreads();                                   // B4: O3 ready, O2/W3 dead

    // W4 -> LDS (over dead O2); prefetch W5
    bhalf8 w5r[6];
    #pragma unroll
    for (int u = 0; u < 6; ++u)
        w5r[u] = ((const bhalf8*)w5)[u * 512 + tid];
    #pragma unroll
    for (int u = 0; u < 3; ++u)
        *(bhalf8*)(pool + 47104 + wswz<64>(u * 512 + tid)) = w4r[u];
    __syncthreads();                                   // B5: W4 visible

    kdlayer<128, 64, 64>(pool, 26624, 71680, 1536, 47104, b4, tid);
    __syncthreads();                                   // B6: O4 ready, O3/W4 dead

    // W5 -> LDS (over dead W3/O3)
    #pragma unroll
    for (int u = 0; u < 6; ++u)
        *(bhalf8*)(pool + 2048 + wswz<64>(u * 512 + tid)) = w5r[u];
    __syncthreads();                                   // B7: W5 visible

    kdlayer<64, 64, 128>(pool, 71680, 51200, 1792, 2048, b5, tid);
    __syncthreads();                                   // B8: O5 ready

    // write out O5 [32][128] bf16: unswizzle on read, coalesced global store
    {
        char* dst = (char*)(outp + (size_t)b * 32 * 128);
        const int off = tid * 16;
        const bhalf8 v = *(const bhalf8*)(pool + 51200 +
                                          swaddr<256>(off >> 8, off & 255));
        *(bhalf8*)(dst + off) = v;
    }
}

// ---------------------------------------------------------------------------
// Unified bf16 MFMA GEMM layer, single-position staging (L6, L7).
// Tile: BT rows x 64 feats. KS = min(CIN,128).  First barrier skipped
// (pp==0 && k0==0: nothing to protect).
// ---------------------------------------------------------------------------
template<int CIN, int BT>
__global__ __launch_bounds__(256)
void kdmfma_kernel(const unsigned short* __restrict__ act,
                   const unsigned short* __restrict__ Wq,
                   const float* __restrict__ bias,
                   const int*   __restrict__ sel,
                   unsigned short* __restrict__ out,
                   int feat, int dim, int nbt) {
    constexpr int KS  = (CIN >= 128) ? 128 : CIN;
    constexpr int NH  = KS / 32;              // mfma k-slices per stage
    constexpr int LDK = KS + 8;
    constexpr int TPA = 256 / BT;             // threads per A row
    constexpr int EA  = KS / TPA;             // A elems per thread (mult of 8)
    constexpr int NSA = EA / 8;               // bhalf8 per thread (A)
    constexpr int NSW = KS / 32;              // bhalf8 per thread (W, 64 rows)
    constexpr int MF  = 2;                    // frag rows per wave
    constexpr int NF  = (BT == 64) ? 2 : 1;   // frag cols per wave
    __shared__ __align__(16) unsigned short Ab[BT][LDK];
    __shared__ __align__(16) unsigned short Wb[64][LDK];

    const int dimh = dim >> 1;
    const int bt = blockIdx.x % nbt;
    const int j  = blockIdx.x / nbt;
    const int f0 = blockIdx.y * 64;
    const int b0 = bt * BT;

    const int tid  = threadIdx.x;
    const int lane = tid & 63;
    const int wave = tid >> 6;

    const int srowA = tid / TPA;
    const int kgA   = (tid % TPA) * EA;
    const int srowW = tid >> 2;
    const int kgW   = (tid & 3) * (KS / 4);

    const int rowBase = (BT == 64) ? (wave & 1) * 32 : 0;
    const int colBase = (BT == 64) ? (wave >> 1) * 32 : wave * 16;

    floatx4 acc[2][MF][NF];
    #pragma unroll
    for (int pp = 0; pp < 2; ++pp)
        #pragma unroll
        for (int mi = 0; mi < MF; ++mi)
            #pragma unroll
            for (int ni = 0; ni < NF; ++ni)
                acc[pp][mi][ni] = (floatx4){0.f, 0.f, 0.f, 0.f};
    int qv[2];

    #pragma unroll
    for (int pp = 0; pp < 2; ++pp) {
        const int d = 2 * j + pp;
        const int s = sel[d];
        const int e = 3 * d + s;
        const int q = (e >= dim) + (e >= 2 * dim);
        const int p = e - q * dim;
        qv[pp] = q;

        const unsigned short* Ap = act + ((size_t)(b0 + srowA) * dim + p) * CIN + kgA;
        const unsigned short* Wp = Wq + ((size_t)(3 * (f0 + srowW) + q)) * CIN + kgW;

        bhalf8 pa[NSA], pw[NSW];
        #pragma unroll
        for (int u = 0; u < NSA; ++u)
            pa[u] = *reinterpret_cast<const bhalf8*>(Ap + u * 8);
        #pragma unroll
        for (int u = 0; u < NSW; ++u)
            pw[u] = *reinterpret_cast<const bhalf8*>(Wp + u * 8);

        for (int k0 = 0; k0 < CIN; k0 += KS) {
            if (pp || k0) __syncthreads();   // prior stage's reads complete
            #pragma unroll
            for (int u = 0; u < NSA; ++u)
                *reinterpret_cast<bhalf8*>(&Ab[srowA][kgA + u * 8]) = pa[u];
            #pragma unroll
            for (int u = 0; u < NSW; ++u)
                *reinterpret_cast<bhalf8*>(&Wb[srowW][kgW + u * 8]) = pw[u];
            if (k0 + KS < CIN) {   // prefetch next stage
                #pragma unroll
                for (int u = 0; u < NSA; ++u)
                    pa[u] = *reinterpret_cast<const bhalf8*>(Ap + k0 + KS + u * 8);
                #pragma unroll
                for (int u = 0; u < NSW; ++u)
                    pw[u] = *reinterpret_cast<const bhalf8*>(Wp + k0 + KS + u * 8);
            }
            __syncthreads();

            #pragma unroll
            for (int ks = 0; ks < NH; ++ks) {
                const int kk = ks * 32 + (lane >> 4) * 8;
                bhalf8 aF[MF], bF[NF];
                #pragma unroll
                for (int mi = 0; mi < MF; ++mi)
                    aF[mi] = *reinterpret_cast<const bhalf8*>(
                        &Ab[rowBase + mi * 16 + (lane & 15)][kk]);
                #pragma unroll
                for (int ni = 0; ni < NF; ++ni)
                    bF[ni] = *reinterpret_cast<const bhalf8*>(
                        &Wb[colBase + ni * 16 + (lane & 15)][kk]);
                #pragma unroll
                for (int mi = 0; mi < MF; ++mi)
                    #pragma unroll
                    for (int ni = 0; ni < NF; ++ni)
                        acc[pp][mi][ni] = __builtin_amdgcn_mfma_f32_16x16x32_bf16(
                            aF[mi], bF[ni], acc[pp][mi][ni], 0, 0, 0);
            }
        }
    }

    const int orow = (lane >> 4) << 2;
    const int ocol = lane & 15;
    #pragma unroll
    for (int mi = 0; mi < MF; ++mi)
        #pragma unroll
        for (int ni = 0; ni < NF; ++ni) {
            const int fc = f0 + colBase + ni * 16 + ocol;
            const float bv0 = bias[3 * fc + qv[0]];
            const float bv1 = bias[3 * fc + qv[1]];
            #pragma unroll
            for (int i = 0; i < 4; ++i) {
                const int br = b0 + rowBase + mi * 16 + orow + i;
                const float v = fmaxf(fmaxf(acc[0][mi][ni][i] + bv0,
                                            acc[1][mi][ni][i] + bv1), 0.f);
                out[((size_t)br * dimh + j) * feat + fc] = f2bf(v);
            }
        }
}

// ---------------------------------------------------------------------------
// kdmfma2: CIN=512 tail (L8..L10), BT=32.  Stages BOTH positions per k-stage
// (Ab[2]/Wb[2], 52KB LDS -> 3 blk/CU): barrier pairs 8 -> 4 (first skipped).
// Per-acc k-slice order identical to kdmfma (bitwise same results).
// ---------------------------------------------------------------------------
template<int CIN, int BT>
__global__ __launch_bounds__(256)
void kdmfma2_kernel(const unsigned short* __restrict__ act,
                    const unsigned short* __restrict__ Wq,
                    const float* __restrict__ bias,
                    const int*   __restrict__ sel,
                    unsigned short* __restrict__ out,
                    int feat, int dim, int nbt) {
    constexpr int KS  = 128;
    constexpr int NH  = KS / 32;              // 4
    constexpr int LDK = KS + 8;
    constexpr int TPA = 256 / BT;             // 8
    constexpr int EA  = KS / TPA;             // 16
    constexpr int NSA = EA / 8;               // 2
    constexpr int NSW = KS / 32;              // 4
    constexpr int MF  = 2;
    __shared__ __align__(16) unsigned short Ab[2][BT][LDK];
    __shared__ __align__(16) unsigned short Wb[2][64][LDK];

    const int dimh = dim >> 1;
    const int bt = blockIdx.x % nbt;
    const int j  = blockIdx.x / nbt;
    const int f0 = blockIdx.y * 64;
    const int b0 = bt * BT;

    const int tid  = threadIdx.x;
    const int lane = tid & 63;
    const int wave = tid >> 6;

    const int srowA = tid / TPA;
    const int kgA   = (tid % TPA) * EA;
    const int srowW = tid >> 2;
    const int kgW   = (tid & 3) * (KS / 4);
    const int colBase = wave * 16;

    int qv[2];
    const unsigned short* Ap[2];
    const unsigned short* Wp[2];
    #pragma unroll
    for (int pp = 0; pp < 2; ++pp) {
        const int d = 2 * j + pp;
        const int e = 3 * d + sel[d];
        const int q = (e >= dim) + (e >= 2 * dim);
        const int p = e - q * dim;
        qv[pp] = q;
        Ap[pp] = act + ((size_t)(b0 + srowA) * dim + p) * CIN + kgA;
        Wp[pp] = Wq + ((size_t)(3 * (f0 + srowW) + q)) * CIN + kgW;
    }

    floatx4 acc[2][MF];
    #pragma unroll
    for (int pp = 0; pp < 2; ++pp)
        #pragma unroll
        for (int mi = 0; mi < MF; ++mi)
            acc[pp][mi] = (floatx4){0.f, 0.f, 0.f, 0.f};

    bhalf8 pa[2][NSA], pw[2][NSW];
    #pragma unroll
    for (int pp = 0; pp < 2; ++pp) {
        #pragma unroll
        for (int u = 0; u < NSA; ++u)
            pa[pp][u] = *reinterpret_cast<const bhalf8*>(Ap[pp] + u * 8);
        #pragma unroll
        for (int u = 0; u < NSW; ++u)
            pw[pp][u] = *reinterpret_cast<const bhalf8*>(Wp[pp] + u * 8);
    }

    for (int k0 = 0; k0 < CIN; k0 += KS) {
        if (k0) __syncthreads();   // protect prior stage's fragment reads
        #pragma unroll
        for (int pp = 0; pp < 2; ++pp) {
            #pragma unroll
            for (int u = 0; u < NSA; ++u)
                *reinterpret_cast<bhalf8*>(&Ab[pp][srowA][kgA + u * 8]) = pa[pp][u];
            #pragma unroll
            for (int u = 0; u < NSW; ++u)
                *reinterpret_cast<bhalf8*>(&Wb[pp][srowW][kgW + u * 8]) = pw[pp][u];
        }
        if (k0 + KS < CIN) {
            #pragma unroll
            for (int pp = 0; pp < 2; ++pp) {
                #pragma unroll
                for (int u = 0; u < NSA; ++u)
                    pa[pp][u] = *reinterpret_cast<const bhalf8*>(Ap[pp] + k0 + KS + u * 8);
                #pragma unroll
                for (int u = 0; u < NSW; ++u)
                    pw[pp][u] = *reinterpret_cast<const bhalf8*>(Wp[pp] + k0 + KS + u * 8);
            }
        }
        __syncthreads();

        #pragma unroll
        for (int ks = 0; ks < NH; ++ks) {
            const int kk = ks * 32 + (lane >> 4) * 8;
            bhalf8 aF[2][MF], bF[2];
            #pragma unroll
            for (int pp = 0; pp < 2; ++pp) {
                #pragma unroll
                for (int mi = 0; mi < MF; ++mi)
                    aF[pp][mi] = *reinterpret_cast<const bhalf8*>(
                        &Ab[pp][mi * 16 + (lane & 15)][kk]);
                bF[pp] = *reinterpret_cast<const bhalf8*>(
                        &Wb[pp][colBase + (lane & 15)][kk]);
            }
            #pragma unroll
            for (int pp = 0; pp < 2; ++pp)
                #pragma unroll
                for (int mi = 0; mi < MF; ++mi)
                    acc[pp][mi] = __builtin_amdgcn_mfma_f32_16x16x32_bf16(
                        aF[pp][mi], bF[pp], acc[pp][mi], 0, 0, 0);
        }
    }

    const int orow = (lane >> 4) << 2;
    const int ocol = lane & 15;
    #pragma unroll
    for (int mi = 0; mi < MF; ++mi) {
        const int fc = f0 + colBase + ocol;
        const float bv0 = bias[3 * fc + qv[0]];
        const float bv1 = bias[3 * fc + qv[1]];
        #pragma unroll
        for (int i = 0; i < 4; ++i) {
            const int br = b0 + mi * 16 + orow + i;
            const float v = fmaxf(fmaxf(acc[0][mi][i] + bv0,
                                        acc[1][mi][i] + bv1), 0.f);
            out[((size_t)br * dimh + j) * feat + fc] = f2bf(v);
        }
    }
}

// FC (1024 -> 16) + log_softmax; input bf16 [B, 1024].
__global__ __launch_bounds__(256)
void fc_lsm_kernel(const unsigned short* __restrict__ y,
                   const float* __restrict__ Wfc,
                   const float* __restrict__ bfc,
                   float* __restrict__ out) {
    const int b   = blockIdx.x;
    const int tid = threadIdx.x;
    __shared__ __align__(16) float ys[1024];
    __shared__ float lg[16];

    {
        const ushort4 v = reinterpret_cast<const ushort4*>(y + (size_t)b * 1024)[tid];
        ys[tid * 4 + 0] = bf2f(v.x);
        ys[tid * 4 + 1] = bf2f(v.y);
        ys[tid * 4 + 2] = bf2f(v.z);
        ys[tid * 4 + 3] = bf2f(v.w);
    }
    __syncthreads();

    const int l = tid >> 4, lane = tid & 15;
    const float4* w4 = reinterpret_cast<const float4*>(Wfc + (size_t)l * 1024);
    const float4* y4 = reinterpret_cast<const float4*>(ys);
    float p = 0.f;
    #pragma unroll
    for (int i = 0; i < 16; ++i) {
        const float4 a = y4[lane + 16 * i];
        const float4 w = w4[lane + 16 * i];
        p += a.x * w.x + a.y * w.y + a.z * w.z + a.w * w.w;
    }
    #pragma unroll
    for (int off = 8; off > 0; off >>= 1) p += __shfl_down(p, off, 16);
    if (lane == 0) lg[l] = p + bfc[l];
    __syncthreads();

    if (tid < 16) {
        float m = -1e30f;
        #pragma unroll
        for (int i = 0; i < 16; ++i) m = fmaxf(m, lg[i]);
        float s = 0.f;
        #pragma unroll
        for (int i = 0; i < 16; ++i) s += expf(lg[i] - m);
        out[b * 16 + tid] = lg[tid] - m - logf(s);
    }
}

extern "C" void kernel_launch(void* const* d_in, const int* in_sizes, int n_in,
                              void* d_out, int out_size, void* d_ws, size_t ws_size,
                              hipStream_t stream) {
    static const int LFEAT[11] = {8, 32, 64, 64, 64, 128, 256, 512, 512, 512, 1024};
    static const int LDIM[11]  = {2048, 1024, 512, 256, 128, 64, 32, 16, 8, 4, 2};
    static const int LCIN[11]  = {3, 8, 32, 64, 64, 64, 128, 256, 512, 512, 512};

    const float* x = (const float*)d_in[0];
    const int B = in_sizes[0] / (3 * 2048);   // 512

    const size_t slot = (size_t)B * 32 * 512;   // floats
    float* bufA = (float*)d_ws;
    float* bufB = bufA + slot;
    unsigned short* wq = (unsigned short*)(bufB + slot);

    const float* W[11]; const float* bi[11]; const int* sl[11];
    for (int i = 0; i < 11; ++i) {
        W[i]  = (const float*)d_in[12 + 2 * i];
        bi[i] = (const float*)d_in[13 + 2 * i];
        sl[i] = (const int*)d_in[1 + i];
    }

    unsigned short* wqp[11];
    {
        size_t off = 0;
        for (int i = 2; i <= 10; ++i) {
            wqp[i] = wq + off;
            off += (size_t)3 * LFEAT[i] * LCIN[i];
        }
    }

    unsigned short* actA = (unsigned short*)bufA;
    unsigned short* actB = (unsigned short*)bufB;

    // W2..W5 -> bf16 (tiny; must precede chain)
    {
        WPrep wp;
        for (int i = 2; i <= 5; ++i) {
            wp.src[i - 2] = W[i];
            wp.dst[i - 2] = wqp[i];
            wp.n4[i - 2]  = (3 * LFEAT[i] * LCIN[i]) / 4;
        }
        wp.src[4] = nullptr; wp.dst[4] = nullptr; wp.n4[4] = 0;
        wprep25_kernel<<<64, 256, 0, stream>>>(wp);
    }

    // L0..L5 fused chain (+W6..W10 prep blocks): x -> actA [B,32,128]
    {
        WPrep wp;
        for (int i = 6; i <= 10; ++i) {
            wp.src[i - 6] = W[i];
            wp.dst[i - 6] = wqp[i];
            wp.n4[i - 6]  = (3 * LFEAT[i] * LCIN[i]) / 4;
        }
        chain_kernel<<<B + 256, 512, 0, stream>>>(
            x, W[0], bi[0], sl[0], W[1], bi[1], sl[1], actA,
            wqp[2], bi[2], sl[2], wqp[3], bi[3], sl[3],
            wqp[4], bi[4], sl[4], wqp[5], bi[5], sl[5],
            wp, B);
    }

    const int nbt64 = B / 64;   // 8
    const int nbt32 = B / 32;   // 16

    // L6, L7: BT=64 single-position staging
    {   dim3 g((LDIM[6]/2) * nbt64, LFEAT[6]/64);
        kdmfma_kernel<128, 64><<<g, 256, 0, stream>>>(actA, wqp[6], bi[6], sl[6], actB, LFEAT[6], LDIM[6], nbt64); }
    {   dim3 g((LDIM[7]/2) * nbt64, LFEAT[7]/64);
        kdmfma_kernel<256, 64><<<g, 256, 0, stream>>>(actB, wqp[7], bi[7], sl[7], actA, LFEAT[7], LDIM[7], nbt64); }

    // L8..L10: BT=32 both-position staging (kdmfma2)
    {   dim3 g((LDIM[8]/2) * nbt32, LFEAT[8]/64);
        kdmfma2_kernel<512, 32><<<g, 256, 0, stream>>>(actA, wqp[8], bi[8], sl[8], actB, LFEAT[8], LDIM[8], nbt32); }
    {   dim3 g((LDIM[9]/2) * nbt32, LFEAT[9]/64);
        kdmfma2_kernel<512, 32><<<g, 256, 0, stream>>>(actB, wqp[9], bi[9], sl[9], actA, LFEAT[9], LDIM[9], nbt32); }
    {   dim3 g((LDIM[10]/2) * nbt32, LFEAT[10]/64);
        kdmfma2_kernel<512, 32><<<g, 256, 0, stream>>>(actA, wqp[10], bi[10], sl[10], actB, LFEAT[10], LDIM[10], nbt32); }

    // FC + log_softmax
    fc_lsm_kernel<<<B, 256, 0, stream>>>(actB, (const float*)d_in[34],
                                         (const float*)d_in[35], (float*)d_out);
}